// Round 2
// baseline (778.007 us; speedup 1.0000x reference)
//
#include <hip/hip_runtime.h>

#define S_LEN 2048
#define HID_DIM 4096
#define NH 32
#define NKV 8
#define HD 128
#define SCALE_F 0.08838834764831845f

typedef unsigned short u16;
typedef __attribute__((ext_vector_type(8))) __bf16 bf16x8;
typedef __attribute__((ext_vector_type(4))) float f32x4;

__device__ __forceinline__ u16 f2bf(float f) {
  unsigned u = __float_as_uint(f);
  return (u16)((u + 0x7fffu + ((u >> 16) & 1u)) >> 16);
}

__device__ __forceinline__ void gl_lds16(const u16* g, u16* l) {
  __builtin_amdgcn_global_load_lds(
      (const __attribute__((address_space(1))) unsigned int*)g,
      (__attribute__((address_space(3))) unsigned int*)l, 16, 0, 0);
}

// ---------------- elementwise / layout kernels ----------------

__global__ void k_f32_to_bf16(const float* __restrict__ in, u16* __restrict__ out, long n4) {
  long i = (long)blockIdx.x * blockDim.x + threadIdx.x;
  if (i >= n4) return;
  float4 v = ((const float4*)in)[i];
  ushort4 o;
  o.x = f2bf(v.x); o.y = f2bf(v.y); o.z = f2bf(v.z); o.w = f2bf(v.w);
  ((ushort4*)out)[i] = o;
}

// out[c][r] = (bf16) in[r][c], tiled 32x32; batched via blockIdx.z
__global__ void k_transpose_bf16(const float* __restrict__ in, u16* __restrict__ out,
                                 int ld_in, int ld_out, long in_bs, long out_bs) {
  __shared__ float tile[32][33];
  const float* A = in + (long)blockIdx.z * in_bs;
  u16* O = out + (long)blockIdx.z * out_bs;
  int r0 = blockIdx.y * 32, c0 = blockIdx.x * 32;
  int tx = threadIdx.x, ty = threadIdx.y;
  for (int i = ty; i < 32; i += 8) tile[i][tx] = A[(long)(r0 + i) * ld_in + c0 + tx];
  __syncthreads();
  for (int i = ty; i < 32; i += 8) O[(long)(c0 + i) * ld_out + r0 + tx] = f2bf(tile[tx][i]);
}

__global__ void k_norm_to_bc(const float* __restrict__ norm, u16* __restrict__ bc) {
  int h = blockIdx.y;
  int i = blockIdx.x * 256 + threadIdx.x;  // 0..16383
  bc[(long)h * 32768 + 16384 + i] = f2bf(norm[(long)h * 16384 + i]);
}

// ---------------- GEMM: C[M,N] f32 = A[M,K]bf16 @ Bt[N,K]bf16^T ----------------
// 128x128 tile, BK=32, 4 waves (2x2), each wave 64x64 via 4x4 16x16x32 MFMA.

__global__ __launch_bounds__(256) void k_gemm_bt(
    const u16* __restrict__ A, const u16* __restrict__ Bt, float* __restrict__ C,
    int K, int lda, int ldb, int ldc,
    long strideA, long strideB, long strideC, int bmodB) {
  __shared__ u16 As[128 * 32];
  __shared__ u16 Bs[128 * 32];
  const int bz = blockIdx.z;
  A += (long)bz * strideA;
  Bt += (long)(bz % bmodB) * strideB;
  C += (long)bz * strideC;
  const int n0 = blockIdx.x * 128, m0 = blockIdx.y * 128;
  const int tid = threadIdx.x, wid = tid >> 6, lane = tid & 63;
  const int l15 = lane & 15, lhi = lane >> 4;
  const int wm = wid >> 1, wn = wid & 1;
  const int srow = lane >> 2, scol = (lane & 3) * 8;

  f32x4 acc[4][4];
#pragma unroll
  for (int i = 0; i < 4; i++)
#pragma unroll
    for (int j = 0; j < 4; j++) acc[i][j] = (f32x4){0.f, 0.f, 0.f, 0.f};

  for (int k0 = 0; k0 < K; k0 += 32) {
    __syncthreads();
#pragma unroll
    for (int j = 0; j < 2; j++) {
      int chunk = j * 4 + wid;          // 0..7, wave-uniform
      int row = chunk * 16 + srow;      // 0..127
      gl_lds16(A + (long)(m0 + row) * lda + k0 + scol, &As[chunk * 512]);
      gl_lds16(Bt + (long)(n0 + row) * ldb + k0 + scol, &Bs[chunk * 512]);
    }
    asm volatile("s_waitcnt vmcnt(0)" ::: "memory");
    __syncthreads();
    bf16x8 af[4], bfr[4];
#pragma unroll
    for (int mi = 0; mi < 4; mi++)
      af[mi] = *(const bf16x8*)&As[(wm * 64 + mi * 16 + l15) * 32 + lhi * 8];
#pragma unroll
    for (int ni = 0; ni < 4; ni++)
      bfr[ni] = *(const bf16x8*)&Bs[(wn * 64 + ni * 16 + l15) * 32 + lhi * 8];
#pragma unroll
    for (int mi = 0; mi < 4; mi++)
#pragma unroll
      for (int ni = 0; ni < 4; ni++)
        acc[mi][ni] = __builtin_amdgcn_mfma_f32_16x16x32_bf16(af[mi], bfr[ni], acc[mi][ni], 0, 0, 0);
  }
#pragma unroll
  for (int mi = 0; mi < 4; mi++)
#pragma unroll
    for (int ni = 0; ni < 4; ni++)
#pragma unroll
      for (int j = 0; j < 4; j++) {
        int row = m0 + wm * 64 + mi * 16 + lhi * 4 + j;
        int col = n0 + wn * 64 + ni * 16 + l15;
        C[(long)row * ldc + col] = acc[mi][ni][j];
      }
}

// ---------------- qn / kn : (elu(x)+1) normalized over HD ----------------

__global__ void k_qn(const float* __restrict__ proj, u16* __restrict__ outb,
                     float* __restrict__ outf, int H) {
  int s = blockIdx.x, h = blockIdx.y, l = threadIdx.x;  // 64 threads
  const float* row = proj + (long)s * (H * HD) + h * HD;
  float x0 = row[l], x1 = row[l + 64];
  float f0 = x0 > 0.f ? x0 + 1.f : __expf(x0);
  float f1 = x1 > 0.f ? x1 + 1.f : __expf(x1);
  float sum = f0 + f1;
#pragma unroll
  for (int m = 32; m >= 1; m >>= 1) sum += __shfl_xor(sum, m);
  float inv = 1.f / (sum + 1e-8f);
  float y0 = f0 * inv, y1 = f1 * inv;
  long o = ((long)h * S_LEN + s) * HD;
  outb[o + l] = f2bf(y0);
  outb[o + l + 64] = f2bf(y1);
  if (outf) { outf[o + l] = y0; outf[o + l + 64] = y1; }
}

// ---------------- RoPE ----------------

__global__ void k_rope_table(const int* __restrict__ pos, float* __restrict__ ct,
                             float* __restrict__ st) {
  int s = blockIdx.x, i = threadIdx.x;  // 64 threads
  float p = (float)pos[s];
  float ang = p * expf(-(float)i * (9.210340371976184f / 64.0f));
  ct[s * 64 + i] = cosf(ang);
  st[s * 64 + i] = sinf(ang);
}

__global__ void k_rope(const float* __restrict__ proj, const float* __restrict__ ct,
                       const float* __restrict__ st, u16* __restrict__ outb, int H) {
  int s = blockIdx.x, h = blockIdx.y, l = threadIdx.x;  // 64 threads
  const float* row = proj + (long)s * (H * HD) + h * HD;
  float x0 = row[l], x1 = row[l + 64];
  float c = ct[s * 64 + l], sn = st[s * 64 + l];
  long o = ((long)h * S_LEN + s) * HD;
  outb[o + l] = f2bf(x0 * c - x1 * sn);
  outb[o + l + 64] = f2bf(x1 * c + x0 * sn);
}

// ---------------- U = v - v_ret ----------------

__global__ void k_uvret(const float* __restrict__ rawk, const float* __restrict__ vproj,
                        float* __restrict__ U) {
  int s = blockIdx.x, h = blockIdx.y, e = threadIdx.x;  // 128 threads
  long base = ((long)h * S_LEN + s) * 256;
  float num = rawk[base + e], den = rawk[base + 128 + e];
  U[((long)h * S_LEN + s) * HD + e] =
      vproj[(long)s * (NKV * HD) + h * HD + e] - num / (den + 1e-8f);
}

// ---------------- flash attention (causal, GQA, no-max online softmax) ----------------

__global__ __launch_bounds__(256) void k_flash(
    const u16* __restrict__ qr, const u16* __restrict__ kr,
    const u16* __restrict__ vt, float* __restrict__ attn) {
  __shared__ u16 Ks[32 * 136];
  __shared__ u16 Vs[128 * 40];
  __shared__ u16 Ps[4][32 * 48];
  const int qb = blockIdx.x, h = blockIdx.y;
  const int hk = h >> 2;  // GROUPS=4, repeat_interleave
  const int tid = threadIdx.x, wid = tid >> 6, lane = tid & 63;
  const int l15 = lane & 15, lhi = lane >> 4;
  const int q0 = qb * 128 + wid * 32;
  const u16* qbase = qr + (long)h * S_LEN * HD;
  const u16* kb0 = kr + (long)hk * S_LEN * HD;
  const u16* vb0 = vt + (long)hk * HD * S_LEN;

  bf16x8 aq[2][4];
#pragma unroll
  for (int mi = 0; mi < 2; mi++)
#pragma unroll
    for (int kc = 0; kc < 4; kc++)
      aq[mi][kc] = *(const bf16x8*)&qbase[(long)(q0 + mi * 16 + l15) * HD + kc * 32 + lhi * 8];

  f32x4 accO[2][8];
#pragma unroll
  for (int i = 0; i < 2; i++)
#pragma unroll
    for (int j = 0; j < 8; j++) accO[i][j] = (f32x4){0.f, 0.f, 0.f, 0.f};
  float rs[2][4] = {{0.f, 0.f, 0.f, 0.f}, {0.f, 0.f, 0.f, 0.f}};

  const int nt = qb * 4 + 4;
  for (int t = 0; t < nt; t++) {
    __syncthreads();
    // stage K tile [32][128] -> Ks [32][136]
#pragma unroll
    for (int i = 0; i < 2; i++) {
      int ch = tid + 256 * i;
      int r = ch >> 4, c = (ch & 15) * 8;
      bf16x8 v = *(const bf16x8*)&kb0[(long)(t * 32 + r) * HD + c];
      *(bf16x8*)&Ks[r * 136 + c] = v;
    }
    // stage Vt tile [128][32] -> Vs [128][40]
#pragma unroll
    for (int i = 0; i < 2; i++) {
      int ch = tid + 256 * i;
      int r = ch >> 2, c = (ch & 3) * 8;
      bf16x8 v = *(const bf16x8*)&vb0[(long)r * S_LEN + t * 32 + c];
      *(bf16x8*)&Vs[r * 40 + c] = v;
    }
    __syncthreads();
    bool active = (t * 32 <= q0 + 31);
    if (active) {
      f32x4 accS[2][2];
#pragma unroll
      for (int i = 0; i < 2; i++)
#pragma unroll
        for (int j = 0; j < 2; j++) accS[i][j] = (f32x4){0.f, 0.f, 0.f, 0.f};
      bf16x8 bk[2][4];
#pragma unroll
      for (int ni = 0; ni < 2; ni++)
#pragma unroll
        for (int kc = 0; kc < 4; kc++)
          bk[ni][kc] = *(const bf16x8*)&Ks[(ni * 16 + l15) * 136 + kc * 32 + lhi * 8];
#pragma unroll
      for (int mi = 0; mi < 2; mi++)
#pragma unroll
        for (int ni = 0; ni < 2; ni++)
#pragma unroll
          for (int kc = 0; kc < 4; kc++)
            accS[mi][ni] =
                __builtin_amdgcn_mfma_f32_16x16x32_bf16(aq[mi][kc], bk[ni][kc], accS[mi][ni], 0, 0, 0);
      u16* P = Ps[wid];
#pragma unroll
      for (int mi = 0; mi < 2; mi++)
#pragma unroll
        for (int j = 0; j < 4; j++) {
          int row = q0 + mi * 16 + lhi * 4 + j;
#pragma unroll
          for (int ni = 0; ni < 2; ni++) {
            int col = t * 32 + ni * 16 + l15;
            float p = (col <= row) ? __expf(accS[mi][ni][j] * SCALE_F) : 0.f;
            rs[mi][j] += p;
            P[(mi * 16 + lhi * 4 + j) * 48 + ni * 16 + l15] = f2bf(p);
          }
        }
    }
    __syncthreads();
    if (active) {
      bf16x8 ap[2], bv[8];
#pragma unroll
      for (int mi = 0; mi < 2; mi++)
        ap[mi] = *(const bf16x8*)&Ps[wid][(mi * 16 + l15) * 48 + lhi * 8];
#pragma unroll
      for (int nj = 0; nj < 8; nj++)
        bv[nj] = *(const bf16x8*)&Vs[(nj * 16 + l15) * 40 + lhi * 8];
#pragma unroll
      for (int mi = 0; mi < 2; mi++)
#pragma unroll
        for (int nj = 0; nj < 8; nj++)
          accO[mi][nj] = __builtin_amdgcn_mfma_f32_16x16x32_bf16(ap[mi], bv[nj], accO[mi][nj], 0, 0, 0);
    }
  }
  // finish: row-sum reduce over the 16 lanes holding each row, then normalize + store
#pragma unroll
  for (int mi = 0; mi < 2; mi++)
#pragma unroll
    for (int j = 0; j < 4; j++) {
      float v = rs[mi][j];
      v += __shfl_xor(v, 1);
      v += __shfl_xor(v, 2);
      v += __shfl_xor(v, 4);
      v += __shfl_xor(v, 8);
      rs[mi][j] = 1.f / v;
    }
  float* ob = attn + (long)h * S_LEN * HD;
#pragma unroll
  for (int mi = 0; mi < 2; mi++)
#pragma unroll
    for (int nj = 0; nj < 8; nj++)
#pragma unroll
      for (int j = 0; j < 4; j++) {
        int row = q0 + mi * 16 + lhi * 4 + j;
        int col = nj * 16 + l15;
        ob[(long)row * HD + col] = accO[mi][nj][j] * rs[mi][j];
      }
}

// ---------------- combine gate*mem_out + (1-gate)*attn -> bf16 [S][NH*HD] ----------------

__global__ void k_combine(const float* __restrict__ rawq, const float* __restrict__ attn,
                          const float* __restrict__ beta, u16* __restrict__ comb) {
  int s = blockIdx.x, h = blockIdx.y, d = threadIdx.x;  // 128 threads
  float g = 1.f / (1.f + __expf(-beta[0]));
  long b = ((long)h * S_LEN + s) * 256;
  float mo = rawq[b + d] / (rawq[b + 128 + d] + 1e-8f);
  float ao = attn[((long)h * S_LEN + s) * HD + d];
  comb[(long)s * HID_DIM + h * HD + d] = f2bf(g * mo + (1.f - g) * ao);
}

// ---------------- delta-rule memory / norm updates (f32 exact path) ----------------

__global__ void k_delta_part(const float* __restrict__ knf, const float* __restrict__ U,
                             float* __restrict__ dpart) {
  int d0 = blockIdx.x * 4, h = blockIdx.y, c = blockIdx.z, e = threadIdx.x;
  const float* kh = knf + (long)h * S_LEN * HD + (long)c * 512 * HD;
  const float* Uh = U + (long)h * S_LEN * HD + (long)c * 512 * HD;
  float a0 = 0.f, a1 = 0.f, a2 = 0.f, a3 = 0.f;
  for (int s = 0; s < 512; s++) {
    float u = Uh[(long)s * HD + e];
    a0 += kh[(long)s * HD + d0 + 0] * u;
    a1 += kh[(long)s * HD + d0 + 1] * u;
    a2 += kh[(long)s * HD + d0 + 2] * u;
    a3 += kh[(long)s * HD + d0 + 3] * u;
  }
  long ob = (long)c * (NKV * HD * HD) + (long)h * HD * HD + (long)d0 * HD + e;
  dpart[ob] = a0;
  dpart[ob + HD] = a1;
  dpart[ob + 2 * HD] = a2;
  dpart[ob + 3 * HD] = a3;
}

__global__ void k_delta_reduce(const float* __restrict__ dpart, const float* __restrict__ mem,
                               float* __restrict__ outmem) {
  long i = (long)blockIdx.x * 256 + threadIdx.x;  // 131072
  const long N = (long)NKV * HD * HD;
  float a = dpart[i] + dpart[N + i] + dpart[2 * N + i] + dpart[3 * N + i];
  outmem[i] = mem[i] + a;
}

__global__ void k_norm_part(const float* __restrict__ knf, float* __restrict__ npart) {
  int c = blockIdx.x, h = blockIdx.y, j = threadIdx.x;  // 16 x 8, 128 thr
  const float* kh = knf + (long)h * S_LEN * HD + (long)c * 128 * HD;
  float a = 0.f;
  for (int s = 0; s < 128; s++) a += kh[(long)s * HD + j];
  npart[((long)c * NKV + h) * HD + j] = a;
}

__global__ void k_norm_write(const float* __restrict__ npart, const float* __restrict__ norm,
                             float* __restrict__ outn) {
  int h = blockIdx.x, j = threadIdx.x;  // 8 blocks, 128 thr
  float cs = 0.f;
  for (int c = 0; c < 16; c++) cs += npart[((long)c * NKV + h) * HD + j];
  long ob = (long)h * HD * HD;
  for (int i = 0; i < HD; i++) outn[ob + (long)i * HD + j] = norm[ob + (long)i * HD + j] + cs;
}

// ---------------- host ----------------
// Workspace arena with lifetime-based aliasing (stream-serialized launches).
// Phases: A hs/wq conv + qproj, B kproj, C vproj, D qn/kn/rope, E vt/bc,
// F retrieval gemms, G uvret, H flash, I combine, J out-proj, K delta/norm.
//
// Region map (byte offsets, MB = 1<<20):            lifetime
//  [0,16M)    hsb (A-C) -> rawk (F-G) -> comb (I-J)
//  [16,48M)   wT: wqT/wkT/wvT (A-C) -> rawq.lo (F-I) -> woT (J)
//  [48,80M)   qf (A-D) -> rawq.hi (F-I)
//  [80,88M)   kf (B-D) -> vtb [80,84M) + bc [84,84.5M) (E-H / E-F)
//  [88,96M)   vf (C-G) -> attn.lo
//  [88,120M)  attn (H-I)  (vf dead after G, qnb/knb dead after F)
//  [96,112M)  qnb (D-F)
//  [112,116M) knb (D-F)
//  [120,128M) knf (D-K)
//  [128,144M) qrb (D-H)
//  [144,148M) krb (D-H)
//  [148,156M) Ub (G-K)
//  [156,157M) ctab/stab (D)
//  [157,159M) dpart (K)
//  [159M,+64K) npart (K)
// Peak ~159.1 MB.

extern "C" void kernel_launch(void* const* d_in, const int* in_sizes, int n_in,
                              void* d_out, int out_size, void* d_ws, size_t ws_size,
                              hipStream_t stream) {
  const float* hs = (const float*)d_in[0];
  const int* pos = (const int*)d_in[1];
  const float* wq = (const float*)d_in[2];
  const float* wk = (const float*)d_in[3];
  const float* wv = (const float*)d_in[4];
  const float* wo = (const float*)d_in[5];
  const float* memf = (const float*)d_in[6];
  const float* normf = (const float*)d_in[7];
  const float* beta = (const float*)d_in[8];
  (void)in_sizes; (void)n_in; (void)out_size; (void)ws_size;

  float* out = (float*)d_out;
  float* out_mem = out + (long)S_LEN * HID_DIM;
  float* out_norm = out_mem + NKV * HD * HD;

  const size_t MB = 1u << 20;
  char* w = (char*)d_ws;
  u16* hsb    = (u16*)(w + 0);
  float* rawk = (float*)(w + 0);
  u16* comb   = (u16*)(w + 0);
  u16* wT     = (u16*)(w + 16 * MB);
  float* rawq = (float*)(w + 16 * MB);
  float* qf   = (float*)(w + 48 * MB);
  float* kf   = (float*)(w + 80 * MB);
  u16* vtb    = (u16*)(w + 80 * MB);
  u16* bc     = (u16*)(w + 84 * MB);
  float* vf   = (float*)(w + 88 * MB);
  float* attn = (float*)(w + 88 * MB);
  u16* qnb    = (u16*)(w + 96 * MB);
  u16* knb    = (u16*)(w + 112 * MB);
  float* knf  = (float*)(w + 120 * MB);
  u16* qrb    = (u16*)(w + 128 * MB);
  u16* krb    = (u16*)(w + 144 * MB);
  float* Ub   = (float*)(w + 148 * MB);
  float* ctab = (float*)(w + 156 * MB);
  float* stab = (float*)(w + 156 * MB + 512 * 1024);
  float* dpart= (float*)(w + 157 * MB);
  float* npart= (float*)(w + 159 * MB);

  // --- A: hs -> bf16; wq^T; qproj ---
  k_f32_to_bf16<<<dim3((S_LEN * HID_DIM / 4 + 255) / 256), dim3(256), 0, stream>>>(
      hs, hsb, (long)(S_LEN * HID_DIM / 4));
  k_transpose_bf16<<<dim3(HID_DIM / 32, HID_DIM / 32, 1), dim3(32, 8), 0, stream>>>(
      wq, wT, HID_DIM, HID_DIM, 0L, 0L);
  k_gemm_bt<<<dim3(HID_DIM / 128, S_LEN / 128, 1), dim3(256), 0, stream>>>(
      hsb, wT, qf, HID_DIM, HID_DIM, HID_DIM, HID_DIM, 0L, 0L, 0L, 1);

  // --- B: wk^T; kproj ---
  k_transpose_bf16<<<dim3(1024 / 32, HID_DIM / 32, 1), dim3(32, 8), 0, stream>>>(
      wk, wT, 1024, HID_DIM, 0L, 0L);
  k_gemm_bt<<<dim3(1024 / 128, S_LEN / 128, 1), dim3(256), 0, stream>>>(
      hsb, wT, kf, HID_DIM, HID_DIM, HID_DIM, 1024, 0L, 0L, 0L, 1);

  // --- C: wv^T; vproj ---
  k_transpose_bf16<<<dim3(1024 / 32, HID_DIM / 32, 1), dim3(32, 8), 0, stream>>>(
      wv, wT, 1024, HID_DIM, 0L, 0L);
  k_gemm_bt<<<dim3(1024 / 128, S_LEN / 128, 1), dim3(256), 0, stream>>>(
      hsb, wT, vf, HID_DIM, HID_DIM, HID_DIM, 1024, 0L, 0L, 0L, 1);

  // --- D: qn/kn, rope ---
  k_qn<<<dim3(S_LEN, NH), dim3(64), 0, stream>>>(qf, qnb, (float*)nullptr, NH);
  k_qn<<<dim3(S_LEN, NKV), dim3(64), 0, stream>>>(kf, knb, knf, NKV);
  k_rope_table<<<dim3(S_LEN), dim3(64), 0, stream>>>(pos, ctab, stab);
  k_rope<<<dim3(S_LEN, NH), dim3(64), 0, stream>>>(qf, ctab, stab, qrb, NH);
  k_rope<<<dim3(S_LEN, NKV), dim3(64), 0, stream>>>(kf, ctab, stab, krb, NKV);

  // --- E: V^T per kv head; bc = [mem^T | norm] bf16 ---
  k_transpose_bf16<<<dim3(HD / 32, S_LEN / 32, NKV), dim3(32, 8), 0, stream>>>(
      vf, vtb, 1024, S_LEN, 128L, (long)(HD * S_LEN));
  k_transpose_bf16<<<dim3(4, 4, NKV), dim3(32, 8), 0, stream>>>(
      memf, bc, HD, HD, (long)(HD * HD), (long)(256 * HD));
  k_norm_to_bc<<<dim3(64, NKV), dim3(256), 0, stream>>>(normf, bc);

  // --- F: retrieval raws (batched) ---
  k_gemm_bt<<<dim3(2, S_LEN / 128, NH), dim3(256), 0, stream>>>(
      qnb, bc, rawq, HD, HD, HD, 256, (long)(S_LEN * HD), (long)(256 * HD), (long)(S_LEN * 256), NKV);
  k_gemm_bt<<<dim3(2, S_LEN / 128, NKV), dim3(256), 0, stream>>>(
      knb, bc, rawk, HD, HD, HD, 256, (long)(S_LEN * HD), (long)(256 * HD), (long)(S_LEN * 256), NKV);

  // --- G: U = v - v_ret ---
  k_uvret<<<dim3(S_LEN, NKV), dim3(128), 0, stream>>>(rawk, vf, Ub);

  // --- H: attention ---
  k_flash<<<dim3(S_LEN / 128, NH), dim3(256), 0, stream>>>(qrb, krb, vtb, attn);

  // --- I: combine ---
  k_combine<<<dim3(S_LEN, NH), dim3(128), 0, stream>>>(rawq, attn, beta, comb);

  // --- J: wo^T; output projection ---
  k_transpose_bf16<<<dim3(HID_DIM / 32, HID_DIM / 32, 1), dim3(32, 8), 0, stream>>>(
      wo, wT, HID_DIM, HID_DIM, 0L, 0L);
  k_gemm_bt<<<dim3(HID_DIM / 128, S_LEN / 128, 1), dim3(256), 0, stream>>>(
      comb, wT, out, HID_DIM, HID_DIM, HID_DIM, HID_DIM, 0L, 0L, 0L, 1);

  // --- K: memory / norm updates ---
  k_delta_part<<<dim3(32, NKV, 4), dim3(128), 0, stream>>>(knf, Ub, dpart);
  k_delta_reduce<<<dim3(512), dim3(256), 0, stream>>>(dpart, memf, out_mem);
  k_norm_part<<<dim3(16, NKV), dim3(128), 0, stream>>>(knf, npart);
  k_norm_write<<<dim3(NKV), dim3(128), 0, stream>>>(npart, normf, out_norm);
}

// Round 3
// 548.990 us; speedup vs baseline: 1.4172x; 1.4172x over previous
//
#include <hip/hip_runtime.h>

#define S_LEN 2048
#define HID_DIM 4096
#define NH 32
#define NKV 8
#define HD 128
#define QKV_N 6144
#define SCALE_F 0.08838834764831845f

typedef unsigned short u16;
typedef __attribute__((ext_vector_type(8))) __bf16 bf16x8;
typedef __attribute__((ext_vector_type(4))) float f32x4;

__device__ __forceinline__ u16 f2bf(float f) {
  unsigned u = __float_as_uint(f);
  return (u16)((u + 0x7fffu + ((u >> 16) & 1u)) >> 16);
}
__device__ __forceinline__ float bf2f(u16 v) {
  return __uint_as_float((unsigned)v << 16);
}

__device__ __forceinline__ void gl_lds16(const u16* g, u16* l) {
  __builtin_amdgcn_global_load_lds(
      (const __attribute__((address_space(1))) unsigned int*)g,
      (__attribute__((address_space(3))) unsigned int*)l, 16, 0, 0);
}

// ---------------- elementwise / layout kernels ----------------

__global__ void k_f32_to_bf16(const float* __restrict__ in, u16* __restrict__ out, long n4) {
  long i = (long)blockIdx.x * blockDim.x + threadIdx.x;
  if (i >= n4) return;
  float4 v = ((const float4*)in)[i];
  ushort4 o;
  o.x = f2bf(v.x); o.y = f2bf(v.y); o.z = f2bf(v.z); o.w = f2bf(v.w);
  ((ushort4*)out)[i] = o;
}

// out[c][r] = (bf16) in[r][c], tiled 32x32; batched via blockIdx.z
__global__ void k_transpose_bf16(const float* __restrict__ in, u16* __restrict__ out,
                                 int ld_in, int ld_out, long in_bs, long out_bs) {
  __shared__ float tile[32][33];
  const float* A = in + (long)blockIdx.z * in_bs;
  u16* O = out + (long)blockIdx.z * out_bs;
  int r0 = blockIdx.y * 32, c0 = blockIdx.x * 32;
  int tx = threadIdx.x, ty = threadIdx.y;
  for (int i = ty; i < 32; i += 8) tile[i][tx] = A[(long)(r0 + i) * ld_in + c0 + tx];
  __syncthreads();
  for (int i = ty; i < 32; i += 8) O[(long)(c0 + i) * ld_out + r0 + tx] = f2bf(tile[tx][i]);
}

__global__ void k_norm_to_bc(const float* __restrict__ norm, u16* __restrict__ bc) {
  int h = blockIdx.y;
  int i = blockIdx.x * 256 + threadIdx.x;  // 0..16383
  bc[(long)h * 32768 + 16384 + i] = f2bf(norm[(long)h * 16384 + i]);
}

// ---------------- GEMM: C[M,N] = A[M,K]bf16 @ Bt[N,K]bf16^T ----------------
// 128x128 tile, BK=32, 4 waves (2x2), each wave 64x64 via 4x4 16x16x32 MFMA.
// obf: 0 -> f32 output, 1 -> bf16 (u16) output. strideC in elements.

__global__ __launch_bounds__(256) void k_gemm_bt(
    const u16* __restrict__ A, const u16* __restrict__ Bt, void* __restrict__ Cv,
    int K, int lda, int ldb, int ldc,
    long strideA, long strideB, long strideC, int bmodB, int obf) {
  __shared__ u16 As[128 * 32];
  __shared__ u16 Bs[128 * 32];
  const int bz = blockIdx.z;
  A += (long)bz * strideA;
  Bt += (long)(bz % bmodB) * strideB;
  const long coff = (long)bz * strideC;
  const int n0 = blockIdx.x * 128, m0 = blockIdx.y * 128;
  const int tid = threadIdx.x, wid = tid >> 6, lane = tid & 63;
  const int l15 = lane & 15, lhi = lane >> 4;
  const int wm = wid >> 1, wn = wid & 1;
  const int srow = lane >> 2, scol = (lane & 3) * 8;

  f32x4 acc[4][4];
#pragma unroll
  for (int i = 0; i < 4; i++)
#pragma unroll
    for (int j = 0; j < 4; j++) acc[i][j] = (f32x4){0.f, 0.f, 0.f, 0.f};

  for (int k0 = 0; k0 < K; k0 += 32) {
    __syncthreads();
#pragma unroll
    for (int j = 0; j < 2; j++) {
      int chunk = j * 4 + wid;          // 0..7, wave-uniform
      int row = chunk * 16 + srow;      // 0..127
      gl_lds16(A + (long)(m0 + row) * lda + k0 + scol, &As[chunk * 512]);
      gl_lds16(Bt + (long)(n0 + row) * ldb + k0 + scol, &Bs[chunk * 512]);
    }
    asm volatile("s_waitcnt vmcnt(0)" ::: "memory");
    __syncthreads();
    bf16x8 af[4], bfr[4];
#pragma unroll
    for (int mi = 0; mi < 4; mi++)
      af[mi] = *(const bf16x8*)&As[(wm * 64 + mi * 16 + l15) * 32 + lhi * 8];
#pragma unroll
    for (int ni = 0; ni < 4; ni++)
      bfr[ni] = *(const bf16x8*)&Bs[(wn * 64 + ni * 16 + l15) * 32 + lhi * 8];
#pragma unroll
    for (int mi = 0; mi < 4; mi++)
#pragma unroll
      for (int ni = 0; ni < 4; ni++)
        acc[mi][ni] = __builtin_amdgcn_mfma_f32_16x16x32_bf16(af[mi], bfr[ni], acc[mi][ni], 0, 0, 0);
  }
#pragma unroll
  for (int mi = 0; mi < 4; mi++)
#pragma unroll
    for (int ni = 0; ni < 4; ni++)
#pragma unroll
      for (int j = 0; j < 4; j++) {
        long row = m0 + wm * 64 + mi * 16 + lhi * 4 + j;
        long col = n0 + wn * 64 + ni * 16 + l15;
        if (obf)
          ((u16*)Cv)[coff + row * ldc + col] = f2bf(acc[mi][ni][j]);
        else
          ((float*)Cv)[coff + row * ldc + col] = acc[mi][ni][j];
      }
}

// ---------------- fused qn + rope (reads projection row once) ----------------

__global__ void k_rope_table(const int* __restrict__ pos, float* __restrict__ ct,
                             float* __restrict__ st) {
  int s = blockIdx.x, i = threadIdx.x;  // 64 threads
  float p = (float)pos[s];
  float ang = p * expf(-(float)i * (9.210340371976184f / 64.0f));
  ct[s * 64 + i] = cosf(ang);
  st[s * 64 + i] = sinf(ang);
}

__global__ void k_qnrope(const float* __restrict__ qkv, const float* __restrict__ ct,
                         const float* __restrict__ st, u16* __restrict__ qnb,
                         u16* __restrict__ qrb, u16* __restrict__ knb,
                         u16* __restrict__ krb, float* __restrict__ knf) {
  int s = blockIdx.x, y = blockIdx.y, l = threadIdx.x;  // 64 threads
  bool isq = y < NH;
  int h = isq ? y : y - NH;
  const float* row = qkv + (long)s * QKV_N + (isq ? h * HD : HID_DIM + h * HD);
  float x0 = row[l], x1 = row[l + 64];
  // qn = (elu(x)+1) / (sum + eps)
  float f0 = x0 > 0.f ? x0 + 1.f : __expf(x0);
  float f1 = x1 > 0.f ? x1 + 1.f : __expf(x1);
  float sum = f0 + f1;
#pragma unroll
  for (int m = 32; m >= 1; m >>= 1) sum += __shfl_xor(sum, m);
  float inv = 1.f / (sum + 1e-8f);
  float y0 = f0 * inv, y1 = f1 * inv;
  long o = ((long)h * S_LEN + s) * HD;
  // rope
  float c = ct[s * 64 + l], sn = st[s * 64 + l];
  u16 r0 = f2bf(x0 * c - x1 * sn), r1 = f2bf(x1 * c + x0 * sn);
  if (isq) {
    qnb[o + l] = f2bf(y0); qnb[o + l + 64] = f2bf(y1);
    qrb[o + l] = r0; qrb[o + l + 64] = r1;
  } else {
    knb[o + l] = f2bf(y0); knb[o + l + 64] = f2bf(y1);
    knf[o + l] = y0; knf[o + l + 64] = y1;
    krb[o + l] = r0; krb[o + l + 64] = r1;
  }
}

// ---------------- U = v - v_ret ----------------

__global__ void k_uvret(const u16* __restrict__ rawk, const float* __restrict__ qkv,
                        float* __restrict__ U) {
  int s = blockIdx.x, h = blockIdx.y, e = threadIdx.x;  // 128 threads
  long base = ((long)h * S_LEN + s) * 256;
  float num = bf2f(rawk[base + e]), den = bf2f(rawk[base + 128 + e]);
  U[((long)h * S_LEN + s) * HD + e] =
      qkv[(long)s * QKV_N + HID_DIM + NKV * HD + h * HD + e] - num / (den + 1e-8f);
}

// ---------------- flash attention v2 ----------------
// Balanced: block bx handles 64-row q-segments {bx, 31-bx} -> 33 KV-64 tiles each.
// 4 waves x 16 q-rows. XOR-swizzled LDS (col^=(row&7)*8) staged via
// global_load_lds with pre-swizzled global source.

__global__ __launch_bounds__(256) void k_flash2(
    const u16* __restrict__ qr, const u16* __restrict__ kr,
    const u16* __restrict__ vt, float* __restrict__ attn) {
  __shared__ u16 Ks[64 * 128];      // [kv 64][d 128] swizzled
  __shared__ u16 Vs[128 * 64];      // [d 128][kv 64] swizzled
  __shared__ u16 Ps[4][16 * 64];    // per-wave [q 16][kv 64] swizzled
  const int bx = blockIdx.x, h = blockIdx.y;
  const int hk = h >> 2;  // GROUPS=4, repeat_interleave
  const int tid = threadIdx.x, wid = tid >> 6, lane = tid & 63;
  const int l15 = lane & 15, lhi = lane >> 4;
  const u16* qbase = qr + (long)h * S_LEN * HD;
  const u16* kb0 = kr + (long)hk * S_LEN * HD;
  const u16* vb0 = vt + (long)hk * HD * S_LEN;
  float* ob = attn + (long)h * S_LEN * HD;
  u16* P = Ps[wid];

  for (int si = 0; si < 2; si++) {
    const int s = si ? (31 - bx) : bx;
    const int qs = s * 64 + wid * 16;
    bf16x8 aq[4];
#pragma unroll
    for (int kc = 0; kc < 4; kc++)
      aq[kc] = *(const bf16x8*)&qbase[(long)(qs + l15) * HD + kc * 32 + lhi * 8];
    f32x4 accO[8];
#pragma unroll
    for (int i = 0; i < 8; i++) accO[i] = (f32x4){0.f, 0.f, 0.f, 0.f};
    float rs[4] = {0.f, 0.f, 0.f, 0.f};

    for (int t = 0; t <= s; t++) {
      __syncthreads();
      // stage K tile [64][128]: chunk=it*4+wid, lane -> r=chunk*4+(lane>>4)
#pragma unroll
      for (int it = 0; it < 4; it++) {
        int chunk = it * 4 + wid;
        int r = chunk * 4 + (lane >> 4);
        int sc = ((lane & 15) * 8) ^ ((r & 7) * 8);
        gl_lds16(kb0 + (long)(t * 64 + r) * HD + sc, &Ks[chunk * 512]);
      }
      // stage V^T tile [128][64]: r=chunk*8+(lane>>3)
#pragma unroll
      for (int it = 0; it < 4; it++) {
        int chunk = it * 4 + wid;
        int r = chunk * 8 + (lane >> 3);
        int sc = ((lane & 7) * 8) ^ ((r & 7) * 8);
        gl_lds16(vb0 + (long)r * S_LEN + t * 64 + sc, &Vs[chunk * 512]);
      }
      asm volatile("s_waitcnt vmcnt(0)" ::: "memory");
      __syncthreads();

      // QK^T : 16 MFMA
      f32x4 accS[4];
#pragma unroll
      for (int i = 0; i < 4; i++) accS[i] = (f32x4){0.f, 0.f, 0.f, 0.f};
#pragma unroll
      for (int ni = 0; ni < 4; ni++) {
        int row = ni * 16 + l15;
#pragma unroll
        for (int kc = 0; kc < 4; kc++) {
          bf16x8 bk = *(const bf16x8*)&Ks[row * 128 + ((kc * 32 + lhi * 8) ^ ((row & 7) * 8))];
          accS[ni] = __builtin_amdgcn_mfma_f32_16x16x32_bf16(aq[kc], bk, accS[ni], 0, 0, 0);
        }
      }
      // softmax numerators + P write (per-wave LDS, no block barrier needed)
      const bool diag = (t == s);
#pragma unroll
      for (int ni = 0; ni < 4; ni++) {
        int col = t * 64 + ni * 16 + l15;
#pragma unroll
        for (int j = 0; j < 4; j++) {
          int row = qs + lhi * 4 + j;
          float p = (!diag || col <= row) ? __expf(accS[ni][j] * SCALE_F) : 0.f;
          rs[j] += p;
          int pr = lhi * 4 + j;
          P[pr * 64 + ((ni * 16 + l15) ^ ((pr & 7) * 8))] = f2bf(p);
        }
      }
      asm volatile("s_waitcnt lgkmcnt(0)" ::: "memory");
      __builtin_amdgcn_sched_barrier(0);
      // PV : 16 MFMA
      bf16x8 ap[2];
#pragma unroll
      for (int ks = 0; ks < 2; ks++)
        ap[ks] = *(const bf16x8*)&P[l15 * 64 + ((ks * 32 + lhi * 8) ^ ((l15 & 7) * 8))];
#pragma unroll
      for (int nj = 0; nj < 8; nj++) {
        int row = nj * 16 + l15;
#pragma unroll
        for (int ks = 0; ks < 2; ks++) {
          bf16x8 bv = *(const bf16x8*)&Vs[row * 64 + ((ks * 32 + lhi * 8) ^ ((row & 7) * 8))];
          accO[nj] = __builtin_amdgcn_mfma_f32_16x16x32_bf16(ap[ks], bv, accO[nj], 0, 0, 0);
        }
      }
    }
    // row-sum reduce over 16 lanes, normalize, store
#pragma unroll
    for (int j = 0; j < 4; j++) {
      float v = rs[j];
      v += __shfl_xor(v, 1);
      v += __shfl_xor(v, 2);
      v += __shfl_xor(v, 4);
      v += __shfl_xor(v, 8);
      rs[j] = 1.f / v;
    }
#pragma unroll
    for (int nj = 0; nj < 8; nj++)
#pragma unroll
      for (int j = 0; j < 4; j++)
        ob[(long)(qs + lhi * 4 + j) * HD + nj * 16 + l15] = accO[nj][j] * rs[j];
  }
}

// ---------------- combine gate*mem_out + (1-gate)*attn -> bf16 [S][NH*HD] ----------------

__global__ void k_combine(const u16* __restrict__ rawq, const float* __restrict__ attn,
                          const float* __restrict__ beta, u16* __restrict__ comb) {
  int s = blockIdx.x, h = blockIdx.y, d = threadIdx.x;  // 128 threads
  float g = 1.f / (1.f + __expf(-beta[0]));
  long b = ((long)h * S_LEN + s) * 256;
  float mo = bf2f(rawq[b + d]) / (bf2f(rawq[b + 128 + d]) + 1e-8f);
  float ao = attn[((long)h * S_LEN + s) * HD + d];
  comb[(long)s * HID_DIM + h * HD + d] = f2bf(g * mo + (1.f - g) * ao);
}

// ---------------- delta-rule memory / norm updates (f32 exact path) ----------------

__global__ void k_delta_part(const float* __restrict__ knf, const float* __restrict__ U,
                             float* __restrict__ dpart) {
  int d0 = blockIdx.x * 4, h = blockIdx.y, c = blockIdx.z, e = threadIdx.x;
  const float* kh = knf + (long)h * S_LEN * HD + (long)c * 512 * HD;
  const float* Uh = U + (long)h * S_LEN * HD + (long)c * 512 * HD;
  float a0 = 0.f, a1 = 0.f, a2 = 0.f, a3 = 0.f;
  for (int s = 0; s < 512; s++) {
    float u = Uh[(long)s * HD + e];
    a0 += kh[(long)s * HD + d0 + 0] * u;
    a1 += kh[(long)s * HD + d0 + 1] * u;
    a2 += kh[(long)s * HD + d0 + 2] * u;
    a3 += kh[(long)s * HD + d0 + 3] * u;
  }
  long ob = (long)c * (NKV * HD * HD) + (long)h * HD * HD + (long)d0 * HD + e;
  dpart[ob] = a0;
  dpart[ob + HD] = a1;
  dpart[ob + 2 * HD] = a2;
  dpart[ob + 3 * HD] = a3;
}

__global__ void k_delta_reduce(const float* __restrict__ dpart, const float* __restrict__ mem,
                               float* __restrict__ outmem) {
  long i = (long)blockIdx.x * 256 + threadIdx.x;  // 131072
  const long N = (long)NKV * HD * HD;
  float a = dpart[i] + dpart[N + i] + dpart[2 * N + i] + dpart[3 * N + i];
  outmem[i] = mem[i] + a;
}

__global__ void k_norm_part(const float* __restrict__ knf, float* __restrict__ npart) {
  int c = blockIdx.x, h = blockIdx.y, j = threadIdx.x;  // 16 x 8, 128 thr
  const float* kh = knf + (long)h * S_LEN * HD + (long)c * 128 * HD;
  float a = 0.f;
  for (int s = 0; s < 128; s++) a += kh[(long)s * HD + j];
  npart[((long)c * NKV + h) * HD + j] = a;
}

__global__ void k_norm_write(const float* __restrict__ npart, const float* __restrict__ norm,
                             float* __restrict__ outn) {
  int h = blockIdx.x, j = threadIdx.x;  // 8 blocks, 128 thr
  float cs = 0.f;
  for (int c = 0; c < 16; c++) cs += npart[((long)c * NKV + h) * HD + j];
  long ob = (long)h * HD * HD;
  for (int i = 0; i < HD; i++) outn[ob + (long)i * HD + j] = norm[ob + (long)i * HD + j] + cs;
}

// ---------------- host ----------------
// Aliased arena (stream-serialized). Phases:
// A: hs->bf16, wq/wk/wv^T -> wT6, fused QKV gemm -> qkvf
// D: rope_table, qnrope (qnb,qrb,knb,krb,knf)
// E: v^T -> vtb, mem^T/norm -> bc
// F: retrieval gemms -> rawq(bf16), rawk(bf16)
// G: uvret -> Ub   H: flash -> attn   I: combine -> comb
// J: wo^T -> woT, out gemm            K: delta/norm updates
//
// MiB offsets:
//  [0,16)      hsb(A) / qnb(D-F1) / comb(I-J) / dpart+npart(K)
//  [16,64)     wT6(A) / rawq u16 32MiB [16,48) (F1-I) / woT [16,48) (J)
//  [48,56)     rawk u16 (F2-G)
//  [56,57)     ctab,stab (D-)
//  [57,57.5)   bc (E-F)
//  [57.5,65.5) vtb (E-H)
//  [66.5,114.5) qkvf f32 (A-G) / attn [66.5,98.5) (H-I)
//  [114.5,122.5) Ub (G-K)
//  [122.5,130.5) knf (D-K)
//  [130.5,146.5) qrb (D-H)
//  [146.5,150.5) krb (D-H)
//  [150.5,154.5) knb (D-F2)
// Peak 154.5 MiB.

extern "C" void kernel_launch(void* const* d_in, const int* in_sizes, int n_in,
                              void* d_out, int out_size, void* d_ws, size_t ws_size,
                              hipStream_t stream) {
  const float* hs = (const float*)d_in[0];
  const int* pos = (const int*)d_in[1];
  const float* wq = (const float*)d_in[2];
  const float* wk = (const float*)d_in[3];
  const float* wv = (const float*)d_in[4];
  const float* wo = (const float*)d_in[5];
  const float* memf = (const float*)d_in[6];
  const float* normf = (const float*)d_in[7];
  const float* beta = (const float*)d_in[8];
  (void)in_sizes; (void)n_in; (void)out_size; (void)ws_size;

  float* out = (float*)d_out;
  float* out_mem = out + (long)S_LEN * HID_DIM;
  float* out_norm = out_mem + NKV * HD * HD;

  const size_t MB = 1u << 20;
  char* w = (char*)d_ws;
  u16* hsb    = (u16*)(w + 0);
  u16* qnb    = (u16*)(w + 0);
  u16* comb   = (u16*)(w + 0);
  float* dpart= (float*)(w + 0);
  float* npart= (float*)(w + 2 * MB);
  u16* wT6    = (u16*)(w + 16 * MB);
  u16* rawq   = (u16*)(w + 16 * MB);
  u16* woT    = (u16*)(w + 16 * MB);
  u16* rawk   = (u16*)(w + 48 * MB);
  float* ctab = (float*)(w + 56 * MB);
  float* stab = (float*)(w + 56 * MB + 512 * 1024);
  u16* bc     = (u16*)(w + 57 * MB);
  u16* vtb    = (u16*)(w + 57 * MB + 512 * 1024);
  float* qkvf = (float*)(w + 66 * MB + 512 * 1024);
  float* attn = (float*)(w + 66 * MB + 512 * 1024);
  float* Ub   = (float*)(w + 114 * MB + 512 * 1024);
  float* knf  = (float*)(w + 122 * MB + 512 * 1024);
  u16* qrb    = (u16*)(w + 130 * MB + 512 * 1024);
  u16* krb    = (u16*)(w + 146 * MB + 512 * 1024);
  u16* knb    = (u16*)(w + 150 * MB + 512 * 1024);

  // --- A: conversions + fused QKV projection ---
  k_f32_to_bf16<<<dim3((S_LEN * HID_DIM / 4 + 255) / 256), dim3(256), 0, stream>>>(
      hs, hsb, (long)(S_LEN * HID_DIM / 4));
  k_transpose_bf16<<<dim3(128, 128, 1), dim3(32, 8), 0, stream>>>(
      wq, wT6, HID_DIM, HID_DIM, 0L, 0L);
  k_transpose_bf16<<<dim3(32, 128, 1), dim3(32, 8), 0, stream>>>(
      wk, wT6 + (long)HID_DIM * HID_DIM, 1024, HID_DIM, 0L, 0L);
  k_transpose_bf16<<<dim3(32, 128, 1), dim3(32, 8), 0, stream>>>(
      wv, wT6 + (long)(HID_DIM + 1024) * HID_DIM, 1024, HID_DIM, 0L, 0L);
  k_gemm_bt<<<dim3(QKV_N / 128, S_LEN / 128, 1), dim3(256), 0, stream>>>(
      hsb, wT6, qkvf, HID_DIM, HID_DIM, HID_DIM, QKV_N, 0L, 0L, 0L, 1, 0);

  // --- D: qn + rope fused ---
  k_rope_table<<<dim3(S_LEN), dim3(64), 0, stream>>>(pos, ctab, stab);
  k_qnrope<<<dim3(S_LEN, NH + NKV), dim3(64), 0, stream>>>(
      qkvf, ctab, stab, qnb, qrb, knb, krb, knf);

  // --- E: V^T per kv head; bc = [mem^T | norm] bf16 ---
  k_transpose_bf16<<<dim3(HD / 32, S_LEN / 32, NKV), dim3(32, 8), 0, stream>>>(
      qkvf + HID_DIM + NKV * HD, vtb, QKV_N, S_LEN, 128L, (long)(HD * S_LEN));
  k_transpose_bf16<<<dim3(4, 4, NKV), dim3(32, 8), 0, stream>>>(
      memf, bc, HD, HD, (long)(HD * HD), (long)(256 * HD));
  k_norm_to_bc<<<dim3(64, NKV), dim3(256), 0, stream>>>(normf, bc);

  // --- F: retrieval raws (batched, bf16 out) ---
  k_gemm_bt<<<dim3(2, S_LEN / 128, NH), dim3(256), 0, stream>>>(
      qnb, bc, rawq, HD, HD, HD, 256, (long)(S_LEN * HD), (long)(256 * HD),
      (long)(S_LEN * 256), NKV, 1);
  k_gemm_bt<<<dim3(2, S_LEN / 128, NKV), dim3(256), 0, stream>>>(
      knb, bc, rawk, HD, HD, HD, 256, (long)(S_LEN * HD), (long)(256 * HD),
      (long)(S_LEN * 256), NKV, 1);

  // --- G: U = v - v_ret ---
  k_uvret<<<dim3(S_LEN, NKV), dim3(128), 0, stream>>>(rawk, qkvf, Ub);

  // --- H: attention ---
  k_flash2<<<dim3(16, NH), dim3(256), 0, stream>>>(qrb, krb, vtb, attn);

  // --- I: combine ---
  k_combine<<<dim3(S_LEN, NH), dim3(128), 0, stream>>>(rawq, attn, beta, comb);

  // --- J: wo^T; output projection ---
  k_transpose_bf16<<<dim3(128, 128, 1), dim3(32, 8), 0, stream>>>(
      wo, woT, HID_DIM, HID_DIM, 0L, 0L);
  k_gemm_bt<<<dim3(HID_DIM / 128, S_LEN / 128, 1), dim3(256), 0, stream>>>(
      comb, woT, out, HID_DIM, HID_DIM, HID_DIM, HID_DIM, 0L, 0L, 0L, 1, 0);

  // --- K: memory / norm updates ---
  k_delta_part<<<dim3(32, NKV, 4), dim3(128), 0, stream>>>(knf, Ub, dpart);
  k_delta_reduce<<<dim3(512), dim3(256), 0, stream>>>(dpart, memf, out_mem);
  k_norm_part<<<dim3(16, NKV), dim3(128), 0, stream>>>(knf, npart);
  k_norm_write<<<dim3(NKV), dim3(128), 0, stream>>>(npart, normf, out_norm);
}

// Round 4
// 479.527 us; speedup vs baseline: 1.6224x; 1.1449x over previous
//
#include <hip/hip_runtime.h>

#define S_LEN 2048
#define HID_DIM 4096
#define NH 32
#define NKV 8
#define HD 128
#define QKV_N 6144
#define SCALE_F 0.08838834764831845f

typedef unsigned short u16;
typedef __attribute__((ext_vector_type(8))) __bf16 bf16x8;
typedef __attribute__((ext_vector_type(4))) float f32x4;

__device__ __forceinline__ u16 f2bf(float f) {
  unsigned u = __float_as_uint(f);
  return (u16)((u + 0x7fffu + ((u >> 16) & 1u)) >> 16);
}
__device__ __forceinline__ float bf2f(u16 v) {
  return __uint_as_float((unsigned)v << 16);
}

__device__ __forceinline__ void gl_lds16(const u16* g, u16* l) {
  __builtin_amdgcn_global_load_lds(
      (const __attribute__((address_space(1))) unsigned int*)g,
      (__attribute__((address_space(3))) unsigned int*)l, 16, 0, 0);
}

// ---------------- elementwise / layout kernels ----------------

__global__ void k_f32_to_bf16(const float* __restrict__ in, u16* __restrict__ out, long n4) {
  long i = (long)blockIdx.x * blockDim.x + threadIdx.x;
  if (i >= n4) return;
  float4 v = ((const float4*)in)[i];
  ushort4 o;
  o.x = f2bf(v.x); o.y = f2bf(v.y); o.z = f2bf(v.z); o.w = f2bf(v.w);
  ((ushort4*)out)[i] = o;
}

// out[c][r] = (bf16) in[r][c], tiled 32x32; batched via blockIdx.z
__global__ void k_transpose_bf16(const float* __restrict__ in, u16* __restrict__ out,
                                 int ld_in, int ld_out, long in_bs, long out_bs) {
  __shared__ float tile[32][33];
  const float* A = in + (long)blockIdx.z * in_bs;
  u16* O = out + (long)blockIdx.z * out_bs;
  int r0 = blockIdx.y * 32, c0 = blockIdx.x * 32;
  int tx = threadIdx.x, ty = threadIdx.y;
  for (int i = ty; i < 32; i += 8) tile[i][tx] = A[(long)(r0 + i) * ld_in + c0 + tx];
  __syncthreads();
  for (int i = ty; i < 32; i += 8) O[(long)(c0 + i) * ld_out + r0 + tx] = f2bf(tile[tx][i]);
}

__global__ void k_norm_to_bc(const float* __restrict__ norm, u16* __restrict__ bc) {
  int h = blockIdx.y;
  int i = blockIdx.x * 256 + threadIdx.x;  // 0..16383
  bc[(long)h * 32768 + 16384 + i] = f2bf(norm[(long)h * 16384 + i]);
}

// ---------------- GEMM v3: C[M,N] = A[M,K]bf16 @ Bt[N,K]bf16^T ----------------
// BM=256 BN=128 BK=64, 512 thr (8 waves = 4m x 2n, 64x64 per wave).
// Triple-buffered LDS (3 x 48 KiB), stages issued 2 K-tiles ahead, counted
// vmcnt(6) + single raw s_barrier per K-tile (never a full drain mid-loop).
// XOR swizzle: 16B-colblock ^= (row&7) on both stage source and ds_read.

__global__ __launch_bounds__(512, 2) void k_gemm3(
    const u16* __restrict__ A, const u16* __restrict__ Bt, void* __restrict__ Cv,
    int K, int ldc, long strideA, long strideB, long strideC, int bmodB, int obf) {
  __shared__ __align__(16) u16 lds[3 * 24576];  // per buf: A[256][64] then B[128][64]
  const int bz = blockIdx.z;
  const u16* Ap = A + (long)bz * strideA;
  const u16* Bp = Bt + (long)(bz % bmodB) * strideB;
  const long coff = (long)bz * strideC;
  const int n0 = blockIdx.x * 128, m0 = blockIdx.y * 256;
  const int tid = threadIdx.x, wid = tid >> 6, lane = tid & 63;
  const int l15 = lane & 15, lhi = lane >> 4;
  const int wm = wid >> 1, wn = wid & 1;

  // stage offsets (pre-swizzled global source, linear LDS dest)
  long gao[4]; int lao[4];
#pragma unroll
  for (int la = 0; la < 4; la++) {
    int bi = (la * 8 + wid) * 64 + lane;   // 16B-block index 0..2047
    int r = bi >> 3, cb = bi & 7;
    gao[la] = (long)(m0 + r) * K + ((cb ^ (r & 7)) * 8);
    lao[la] = bi * 8;
  }
  long gbo[2]; int lbo[2];
#pragma unroll
  for (int lb = 0; lb < 2; lb++) {
    int bi = (lb * 8 + wid) * 64 + lane;   // 0..1023
    int r = bi >> 3, cb = bi & 7;
    gbo[lb] = (long)(n0 + r) * K + ((cb ^ (r & 7)) * 8);
    lbo[lb] = 16384 + bi * 8;
  }
  // ds_read fragment offsets (swizzled)
  int aoff[4][2], boff[4][2];
#pragma unroll
  for (int q = 0; q < 4; q++)
#pragma unroll
    for (int kk = 0; kk < 2; kk++) {
      int ar = wm * 64 + q * 16 + l15;
      aoff[q][kk] = ar * 64 + (((kk * 4 + lhi) ^ (ar & 7)) * 8);
      int br = wn * 64 + q * 16 + l15;
      boff[q][kk] = 16384 + br * 64 + (((kk * 4 + lhi) ^ (br & 7)) * 8);
    }

  const int KT = K >> 6;
  f32x4 acc[4][4];
#pragma unroll
  for (int i = 0; i < 4; i++)
#pragma unroll
    for (int j = 0; j < 4; j++) acc[i][j] = (f32x4){0.f, 0.f, 0.f, 0.f};

  // prologue: stage tiles 0 and 1
#pragma unroll
  for (int la = 0; la < 4; la++) gl_lds16(Ap + gao[la], &lds[lao[la]]);
#pragma unroll
  for (int lb = 0; lb < 2; lb++) gl_lds16(Bp + gbo[lb], &lds[lbo[lb]]);
  if (KT > 1) {
#pragma unroll
    for (int la = 0; la < 4; la++) gl_lds16(Ap + gao[la] + 64, &lds[24576 + lao[la]]);
#pragma unroll
    for (int lb = 0; lb < 2; lb++) gl_lds16(Bp + gbo[lb] + 64, &lds[24576 + lbo[lb]]);
    asm volatile("s_waitcnt vmcnt(6)" ::: "memory");
  } else {
    asm volatile("s_waitcnt vmcnt(0)" ::: "memory");
  }
  __builtin_amdgcn_s_barrier();
  asm volatile("" ::: "memory");

  int b = 0;
  for (int t = 0; t < KT; ++t) {
    const int sb = (b + 2 >= 3) ? (b - 1) : (b + 2);
    const u16* lA = &lds[b * 24576];
    u16* sB = &lds[sb * 24576];
    const bool dst = (t + 2) < KT;
    const long ko = (long)(t + 2) * 64;

    bf16x8 bB[4][2];
#pragma unroll
    for (int ni = 0; ni < 4; ni++)
#pragma unroll
      for (int kk = 0; kk < 2; kk++) bB[ni][kk] = *(const bf16x8*)&lA[boff[ni][kk]];

    // phase 0
    {
      bf16x8 a0 = *(const bf16x8*)&lA[aoff[0][0]];
      bf16x8 a1 = *(const bf16x8*)&lA[aoff[0][1]];
      if (dst) { gl_lds16(Ap + gao[0] + ko, &sB[lao[0]]); gl_lds16(Ap + gao[1] + ko, &sB[lao[1]]); }
      __builtin_amdgcn_s_setprio(1);
#pragma unroll
      for (int ni = 0; ni < 4; ni++) {
        acc[0][ni] = __builtin_amdgcn_mfma_f32_16x16x32_bf16(a0, bB[ni][0], acc[0][ni], 0, 0, 0);
        acc[0][ni] = __builtin_amdgcn_mfma_f32_16x16x32_bf16(a1, bB[ni][1], acc[0][ni], 0, 0, 0);
      }
      __builtin_amdgcn_s_setprio(0);
    }
    // phase 1
    {
      bf16x8 a0 = *(const bf16x8*)&lA[aoff[1][0]];
      bf16x8 a1 = *(const bf16x8*)&lA[aoff[1][1]];
      if (dst) { gl_lds16(Ap + gao[2] + ko, &sB[lao[2]]); gl_lds16(Ap + gao[3] + ko, &sB[lao[3]]); }
      __builtin_amdgcn_s_setprio(1);
#pragma unroll
      for (int ni = 0; ni < 4; ni++) {
        acc[1][ni] = __builtin_amdgcn_mfma_f32_16x16x32_bf16(a0, bB[ni][0], acc[1][ni], 0, 0, 0);
        acc[1][ni] = __builtin_amdgcn_mfma_f32_16x16x32_bf16(a1, bB[ni][1], acc[1][ni], 0, 0, 0);
      }
      __builtin_amdgcn_s_setprio(0);
    }
    // phase 2
    {
      bf16x8 a0 = *(const bf16x8*)&lA[aoff[2][0]];
      bf16x8 a1 = *(const bf16x8*)&lA[aoff[2][1]];
      if (dst) { gl_lds16(Bp + gbo[0] + ko, &sB[lbo[0]]); gl_lds16(Bp + gbo[1] + ko, &sB[lbo[1]]); }
      __builtin_amdgcn_s_setprio(1);
#pragma unroll
      for (int ni = 0; ni < 4; ni++) {
        acc[2][ni] = __builtin_amdgcn_mfma_f32_16x16x32_bf16(a0, bB[ni][0], acc[2][ni], 0, 0, 0);
        acc[2][ni] = __builtin_amdgcn_mfma_f32_16x16x32_bf16(a1, bB[ni][1], acc[2][ni], 0, 0, 0);
      }
      __builtin_amdgcn_s_setprio(0);
    }
    // phase 3 (no stage)
    {
      bf16x8 a0 = *(const bf16x8*)&lA[aoff[3][0]];
      bf16x8 a1 = *(const bf16x8*)&lA[aoff[3][1]];
      __builtin_amdgcn_s_setprio(1);
#pragma unroll
      for (int ni = 0; ni < 4; ni++) {
        acc[3][ni] = __builtin_amdgcn_mfma_f32_16x16x32_bf16(a0, bB[ni][0], acc[3][ni], 0, 0, 0);
        acc[3][ni] = __builtin_amdgcn_mfma_f32_16x16x32_bf16(a1, bB[ni][1], acc[3][ni], 0, 0, 0);
      }
      __builtin_amdgcn_s_setprio(0);
    }
    if (dst)
      asm volatile("s_waitcnt vmcnt(6)" ::: "memory");
    else
      asm volatile("s_waitcnt vmcnt(0)" ::: "memory");
    __builtin_amdgcn_s_barrier();
    asm volatile("" ::: "memory");
    b = (b + 1 >= 3) ? 0 : (b + 1);
  }

#pragma unroll
  for (int mi = 0; mi < 4; mi++)
#pragma unroll
    for (int ni = 0; ni < 4; ni++)
#pragma unroll
      for (int j = 0; j < 4; j++) {
        long row = m0 + wm * 64 + mi * 16 + lhi * 4 + j;
        long col = n0 + wn * 64 + ni * 16 + l15;
        if (obf)
          ((u16*)Cv)[coff + row * ldc + col] = f2bf(acc[mi][ni][j]);
        else
          ((float*)Cv)[coff + row * ldc + col] = acc[mi][ni][j];
      }
}

// ---------------- fused qn + rope (reads projection row once) ----------------

__global__ void k_rope_table(const int* __restrict__ pos, float* __restrict__ ct,
                             float* __restrict__ st) {
  int s = blockIdx.x, i = threadIdx.x;  // 64 threads
  float p = (float)pos[s];
  float ang = p * expf(-(float)i * (9.210340371976184f / 64.0f));
  ct[s * 64 + i] = cosf(ang);
  st[s * 64 + i] = sinf(ang);
}

__global__ void k_qnrope(const float* __restrict__ qkv, const float* __restrict__ ct,
                         const float* __restrict__ st, u16* __restrict__ qnb,
                         u16* __restrict__ qrb, u16* __restrict__ knb,
                         u16* __restrict__ krb, float* __restrict__ knf) {
  int s = blockIdx.x, y = blockIdx.y, l = threadIdx.x;  // 64 threads
  bool isq = y < NH;
  int h = isq ? y : y - NH;
  const float* row = qkv + (long)s * QKV_N + (isq ? h * HD : HID_DIM + h * HD);
  float x0 = row[l], x1 = row[l + 64];
  float f0 = x0 > 0.f ? x0 + 1.f : __expf(x0);
  float f1 = x1 > 0.f ? x1 + 1.f : __expf(x1);
  float sum = f0 + f1;
#pragma unroll
  for (int m = 32; m >= 1; m >>= 1) sum += __shfl_xor(sum, m);
  float inv = 1.f / (sum + 1e-8f);
  float y0 = f0 * inv, y1 = f1 * inv;
  long o = ((long)h * S_LEN + s) * HD;
  float c = ct[s * 64 + l], sn = st[s * 64 + l];
  u16 r0 = f2bf(x0 * c - x1 * sn), r1 = f2bf(x1 * c + x0 * sn);
  if (isq) {
    qnb[o + l] = f2bf(y0); qnb[o + l + 64] = f2bf(y1);
    qrb[o + l] = r0; qrb[o + l + 64] = r1;
  } else {
    knb[o + l] = f2bf(y0); knb[o + l + 64] = f2bf(y1);
    knf[o + l] = y0; knf[o + l + 64] = y1;
    krb[o + l] = r0; krb[o + l + 64] = r1;
  }
}

// ---------------- U = v - v_ret ----------------

__global__ void k_uvret(const u16* __restrict__ rawk, const float* __restrict__ qkv,
                        float* __restrict__ U) {
  int s = blockIdx.x, h = blockIdx.y, e = threadIdx.x;  // 128 threads
  long base = ((long)h * S_LEN + s) * 256;
  float num = bf2f(rawk[base + e]), den = bf2f(rawk[base + 128 + e]);
  U[((long)h * S_LEN + s) * HD + e] =
      qkv[(long)s * QKV_N + HID_DIM + NKV * HD + h * HD + e] - num / (den + 1e-8f);
}

// ---------------- flash attention v2 ----------------

__global__ __launch_bounds__(256) void k_flash2(
    const u16* __restrict__ qr, const u16* __restrict__ kr,
    const u16* __restrict__ vt, float* __restrict__ attn) {
  __shared__ u16 Ks[64 * 128];      // [kv 64][d 128] swizzled
  __shared__ u16 Vs[128 * 64];      // [d 128][kv 64] swizzled
  __shared__ u16 Ps[4][16 * 64];    // per-wave [q 16][kv 64] swizzled
  const int bx = blockIdx.x, h = blockIdx.y;
  const int hk = h >> 2;  // GROUPS=4, repeat_interleave
  const int tid = threadIdx.x, wid = tid >> 6, lane = tid & 63;
  const int l15 = lane & 15, lhi = lane >> 4;
  const u16* qbase = qr + (long)h * S_LEN * HD;
  const u16* kb0 = kr + (long)hk * S_LEN * HD;
  const u16* vb0 = vt + (long)hk * HD * S_LEN;
  float* ob = attn + (long)h * S_LEN * HD;
  u16* P = Ps[wid];

  for (int si = 0; si < 2; si++) {
    const int s = si ? (31 - bx) : bx;
    const int qs = s * 64 + wid * 16;
    bf16x8 aq[4];
#pragma unroll
    for (int kc = 0; kc < 4; kc++)
      aq[kc] = *(const bf16x8*)&qbase[(long)(qs + l15) * HD + kc * 32 + lhi * 8];
    f32x4 accO[8];
#pragma unroll
    for (int i = 0; i < 8; i++) accO[i] = (f32x4){0.f, 0.f, 0.f, 0.f};
    float rs[4] = {0.f, 0.f, 0.f, 0.f};

    for (int t = 0; t <= s; t++) {
      __syncthreads();
#pragma unroll
      for (int it = 0; it < 4; it++) {
        int chunk = it * 4 + wid;
        int r = chunk * 4 + (lane >> 4);
        int sc = ((lane & 15) * 8) ^ ((r & 7) * 8);
        gl_lds16(kb0 + (long)(t * 64 + r) * HD + sc, &Ks[chunk * 512]);
      }
#pragma unroll
      for (int it = 0; it < 4; it++) {
        int chunk = it * 4 + wid;
        int r = chunk * 8 + (lane >> 3);
        int sc = ((lane & 7) * 8) ^ ((r & 7) * 8);
        gl_lds16(vb0 + (long)r * S_LEN + t * 64 + sc, &Vs[chunk * 512]);
      }
      asm volatile("s_waitcnt vmcnt(0)" ::: "memory");
      __syncthreads();

      f32x4 accS[4];
#pragma unroll
      for (int i = 0; i < 4; i++) accS[i] = (f32x4){0.f, 0.f, 0.f, 0.f};
#pragma unroll
      for (int ni = 0; ni < 4; ni++) {
        int row = ni * 16 + l15;
#pragma unroll
        for (int kc = 0; kc < 4; kc++) {
          bf16x8 bk = *(const bf16x8*)&Ks[row * 128 + ((kc * 32 + lhi * 8) ^ ((row & 7) * 8))];
          accS[ni] = __builtin_amdgcn_mfma_f32_16x16x32_bf16(aq[kc], bk, accS[ni], 0, 0, 0);
        }
      }
      const bool diag = (t == s);
#pragma unroll
      for (int ni = 0; ni < 4; ni++) {
        int col = t * 64 + ni * 16 + l15;
#pragma unroll
        for (int j = 0; j < 4; j++) {
          int row = qs + lhi * 4 + j;
          float p = (!diag || col <= row) ? __expf(accS[ni][j] * SCALE_F) : 0.f;
          rs[j] += p;
          int pr = lhi * 4 + j;
          P[pr * 64 + ((ni * 16 + l15) ^ ((pr & 7) * 8))] = f2bf(p);
        }
      }
      asm volatile("s_waitcnt lgkmcnt(0)" ::: "memory");
      __builtin_amdgcn_sched_barrier(0);
      bf16x8 ap[2];
#pragma unroll
      for (int ks = 0; ks < 2; ks++)
        ap[ks] = *(const bf16x8*)&P[l15 * 64 + ((ks * 32 + lhi * 8) ^ ((l15 & 7) * 8))];
#pragma unroll
      for (int nj = 0; nj < 8; nj++) {
        int row = nj * 16 + l15;
#pragma unroll
        for (int ks = 0; ks < 2; ks++) {
          bf16x8 bv = *(const bf16x8*)&Vs[row * 64 + ((ks * 32 + lhi * 8) ^ ((row & 7) * 8))];
          accO[nj] = __builtin_amdgcn_mfma_f32_16x16x32_bf16(ap[ks], bv, accO[nj], 0, 0, 0);
        }
      }
    }
#pragma unroll
    for (int j = 0; j < 4; j++) {
      float v = rs[j];
      v += __shfl_xor(v, 1);
      v += __shfl_xor(v, 2);
      v += __shfl_xor(v, 4);
      v += __shfl_xor(v, 8);
      rs[j] = 1.f / v;
    }
#pragma unroll
    for (int nj = 0; nj < 8; nj++)
#pragma unroll
      for (int j = 0; j < 4; j++)
        ob[(long)(qs + lhi * 4 + j) * HD + nj * 16 + l15] = accO[nj][j] * rs[j];
  }
}

// ---------------- combine ----------------

__global__ void k_combine(const u16* __restrict__ rawq, const float* __restrict__ attn,
                          const float* __restrict__ beta, u16* __restrict__ comb) {
  int s = blockIdx.x, h = blockIdx.y, d = threadIdx.x;  // 128 threads
  float g = 1.f / (1.f + __expf(-beta[0]));
  long b = ((long)h * S_LEN + s) * 256;
  float mo = bf2f(rawq[b + d]) / (bf2f(rawq[b + 128 + d]) + 1e-8f);
  float ao = attn[((long)h * S_LEN + s) * HD + d];
  comb[(long)s * HID_DIM + h * HD + d] = f2bf(g * mo + (1.f - g) * ao);
}

// ---------------- delta-rule memory / norm updates (f32 exact path) ----------------

__global__ void k_delta_part(const float* __restrict__ knf, const float* __restrict__ U,
                             float* __restrict__ dpart) {
  int d0 = blockIdx.x * 16, h = blockIdx.y, c = blockIdx.z, e = threadIdx.x;
  const float* kh = knf + (long)h * S_LEN * HD + (long)c * 512 * HD;
  const float* Uh = U + (long)h * S_LEN * HD + (long)c * 512 * HD;
  float a[16];
#pragma unroll
  for (int d = 0; d < 16; d++) a[d] = 0.f;
  for (int s = 0; s < 512; s++) {
    float u = Uh[(long)s * HD + e];
    const float* kr = &kh[(long)s * HD + d0];
#pragma unroll
    for (int d = 0; d < 16; d++) a[d] += kr[d] * u;
  }
  long ob = (long)c * (NKV * HD * HD) + (long)h * HD * HD + (long)d0 * HD + e;
#pragma unroll
  for (int d = 0; d < 16; d++) dpart[ob + (long)d * HD] = a[d];
}

__global__ void k_delta_reduce(const float* __restrict__ dpart, const float* __restrict__ mem,
                               float* __restrict__ outmem) {
  long i = (long)blockIdx.x * 256 + threadIdx.x;  // 131072
  const long N = (long)NKV * HD * HD;
  float a = dpart[i] + dpart[N + i] + dpart[2 * N + i] + dpart[3 * N + i];
  outmem[i] = mem[i] + a;
}

__global__ void k_norm_part(const float* __restrict__ knf, float* __restrict__ npart) {
  int c = blockIdx.x, h = blockIdx.y, j = threadIdx.x;  // 16 x 8, 128 thr
  const float* kh = knf + (long)h * S_LEN * HD + (long)c * 128 * HD;
  float a = 0.f;
  for (int s = 0; s < 128; s++) a += kh[(long)s * HD + j];
  npart[((long)c * NKV + h) * HD + j] = a;
}

__global__ void k_norm_write(const float* __restrict__ npart, const float* __restrict__ norm,
                             float* __restrict__ outn) {
  int h = blockIdx.x, j = threadIdx.x;  // 8 blocks, 128 thr
  float cs = 0.f;
  for (int c = 0; c < 16; c++) cs += npart[((long)c * NKV + h) * HD + j];
  long ob = (long)h * HD * HD;
  for (int i = 0; i < HD; i++) outn[ob + (long)i * HD + j] = norm[ob + (long)i * HD + j] + cs;
}

// ---------------- host ----------------
// Aliased arena (stream-serialized), same map as round 2 (peak 154.5 MiB).

extern "C" void kernel_launch(void* const* d_in, const int* in_sizes, int n_in,
                              void* d_out, int out_size, void* d_ws, size_t ws_size,
                              hipStream_t stream) {
  const float* hs = (const float*)d_in[0];
  const int* pos = (const int*)d_in[1];
  const float* wq = (const float*)d_in[2];
  const float* wk = (const float*)d_in[3];
  const float* wv = (const float*)d_in[4];
  const float* wo = (const float*)d_in[5];
  const float* memf = (const float*)d_in[6];
  const float* normf = (const float*)d_in[7];
  const float* beta = (const float*)d_in[8];
  (void)in_sizes; (void)n_in; (void)out_size; (void)ws_size;

  float* out = (float*)d_out;
  float* out_mem = out + (long)S_LEN * HID_DIM;
  float* out_norm = out_mem + NKV * HD * HD;

  const size_t MB = 1u << 20;
  char* w = (char*)d_ws;
  u16* hsb    = (u16*)(w + 0);
  u16* qnb    = (u16*)(w + 0);
  u16* comb   = (u16*)(w + 0);
  float* dpart= (float*)(w + 0);
  float* npart= (float*)(w + 2 * MB);
  u16* wT6    = (u16*)(w + 16 * MB);
  u16* rawq   = (u16*)(w + 16 * MB);
  u16* woT    = (u16*)(w + 16 * MB);
  u16* rawk   = (u16*)(w + 48 * MB);
  float* ctab = (float*)(w + 56 * MB);
  float* stab = (float*)(w + 56 * MB + 512 * 1024);
  u16* bc     = (u16*)(w + 57 * MB);
  u16* vtb    = (u16*)(w + 57 * MB + 512 * 1024);
  float* qkvf = (float*)(w + 66 * MB + 512 * 1024);
  float* attn = (float*)(w + 66 * MB + 512 * 1024);
  float* Ub   = (float*)(w + 114 * MB + 512 * 1024);
  float* knf  = (float*)(w + 122 * MB + 512 * 1024);
  u16* qrb    = (u16*)(w + 130 * MB + 512 * 1024);
  u16* krb    = (u16*)(w + 146 * MB + 512 * 1024);
  u16* knb    = (u16*)(w + 150 * MB + 512 * 1024);

  // --- A: conversions + fused QKV projection ---
  k_f32_to_bf16<<<dim3((S_LEN * HID_DIM / 4 + 255) / 256), dim3(256), 0, stream>>>(
      hs, hsb, (long)(S_LEN * HID_DIM / 4));
  k_transpose_bf16<<<dim3(128, 128, 1), dim3(32, 8), 0, stream>>>(
      wq, wT6, HID_DIM, HID_DIM, 0L, 0L);
  k_transpose_bf16<<<dim3(32, 128, 1), dim3(32, 8), 0, stream>>>(
      wk, wT6 + (long)HID_DIM * HID_DIM, 1024, HID_DIM, 0L, 0L);
  k_transpose_bf16<<<dim3(32, 128, 1), dim3(32, 8), 0, stream>>>(
      wv, wT6 + (long)(HID_DIM + 1024) * HID_DIM, 1024, HID_DIM, 0L, 0L);
  k_gemm3<<<dim3(QKV_N / 128, S_LEN / 256, 1), dim3(512), 0, stream>>>(
      hsb, wT6, qkvf, HID_DIM, QKV_N, 0L, 0L, 0L, 1, 0);

  // --- D: qn + rope fused ---
  k_rope_table<<<dim3(S_LEN), dim3(64), 0, stream>>>(pos, ctab, stab);
  k_qnrope<<<dim3(S_LEN, NH + NKV), dim3(64), 0, stream>>>(
      qkvf, ctab, stab, qnb, qrb, knb, krb, knf);

  // --- E: V^T per kv head; bc = [mem^T | norm] bf16 ---
  k_transpose_bf16<<<dim3(HD / 32, S_LEN / 32, NKV), dim3(32, 8), 0, stream>>>(
      qkvf + HID_DIM + NKV * HD, vtb, QKV_N, S_LEN, 128L, (long)(HD * S_LEN));
  k_transpose_bf16<<<dim3(4, 4, NKV), dim3(32, 8), 0, stream>>>(
      memf, bc, HD, HD, (long)(HD * HD), (long)(256 * HD));
  k_norm_to_bc<<<dim3(64, NKV), dim3(256), 0, stream>>>(normf, bc);

  // --- F: retrieval raws (batched, bf16 out) ---
  k_gemm3<<<dim3(2, 8, NH), dim3(512), 0, stream>>>(
      qnb, bc, rawq, HD, 256, (long)(S_LEN * HD), (long)(256 * HD),
      (long)(S_LEN * 256), NKV, 1);
  k_gemm3<<<dim3(2, 8, NKV), dim3(512), 0, stream>>>(
      knb, bc, rawk, HD, 256, (long)(S_LEN * HD), (long)(256 * HD),
      (long)(S_LEN * 256), NKV, 1);

  // --- G: U = v - v_ret ---
  k_uvret<<<dim3(S_LEN, NKV), dim3(128), 0, stream>>>(rawk, qkvf, Ub);

  // --- H: attention ---
  k_flash2<<<dim3(16, NH), dim3(256), 0, stream>>>(qrb, krb, vtb, attn);

  // --- I: combine ---
  k_combine<<<dim3(S_LEN, NH), dim3(128), 0, stream>>>(rawq, attn, beta, comb);

  // --- J: wo^T; output projection ---
  k_transpose_bf16<<<dim3(128, 128, 1), dim3(32, 8), 0, stream>>>(
      wo, woT, HID_DIM, HID_DIM, 0L, 0L);
  k_gemm3<<<dim3(HID_DIM / 128, S_LEN / 256, 1), dim3(512), 0, stream>>>(
      comb, woT, out, HID_DIM, HID_DIM, 0L, 0L, 0L, 1, 0);

  // --- K: memory / norm updates ---
  k_delta_part<<<dim3(8, NKV, 4), dim3(128), 0, stream>>>(knf, Ub, dpart);
  k_delta_reduce<<<dim3(512), dim3(256), 0, stream>>>(dpart, memf, out_mem);
  k_norm_part<<<dim3(16, NKV), dim3(128), 0, stream>>>(knf, npart);
  k_norm_write<<<dim3(NKV), dim3(128), 0, stream>>>(npart, normf, out_norm);
}

// Round 5
// 467.540 us; speedup vs baseline: 1.6640x; 1.0256x over previous
//
#include <hip/hip_runtime.h>

#define S_LEN 2048
#define HID_DIM 4096
#define NH 32
#define NKV 8
#define HD 128
#define QKV_N 6144
#define SCALE_F 0.08838834764831845f

typedef unsigned short u16;
typedef __attribute__((ext_vector_type(8))) __bf16 bf16x8;
typedef __attribute__((ext_vector_type(4))) float f32x4;

__device__ __forceinline__ u16 f2bf(float f) {
  unsigned u = __float_as_uint(f);
  return (u16)((u + 0x7fffu + ((u >> 16) & 1u)) >> 16);
}
__device__ __forceinline__ float bf2f(u16 v) {
  return __uint_as_float((unsigned)v << 16);
}

__device__ __forceinline__ void gl_lds16(const u16* g, u16* l) {
  __builtin_amdgcn_global_load_lds(
      (const __attribute__((address_space(1))) unsigned int*)g,
      (__attribute__((address_space(3))) unsigned int*)l, 16, 0, 0);
}

// ---------------- elementwise / layout kernels ----------------

__global__ void k_f32_to_bf16(const float* __restrict__ in, u16* __restrict__ out, long n4) {
  long i = (long)blockIdx.x * blockDim.x + threadIdx.x;
  if (i >= n4) return;
  float4 v = ((const float4*)in)[i];
  ushort4 o;
  o.x = f2bf(v.x); o.y = f2bf(v.y); o.z = f2bf(v.z); o.w = f2bf(v.w);
  ((ushort4*)out)[i] = o;
}

// out[c][r] = (bf16) in[r][c], 64x64 tiles, 256 thr; float2 reads, ushort2 writes.
__global__ void k_tr64(const float* __restrict__ in, u16* __restrict__ out,
                       int ld_in, int ld_out, long in_bs, long out_bs) {
  __shared__ float tile[64][65];
  const float* A = in + (long)blockIdx.z * in_bs;
  u16* O = out + (long)blockIdx.z * out_bs;
  int r0 = blockIdx.y * 64, c0 = blockIdx.x * 64;
  int tx = threadIdx.x & 31, ty = threadIdx.x >> 5;  // tx 0..31, ty 0..7
#pragma unroll
  for (int i = 0; i < 8; i++) {
    int r = ty + 8 * i;
    float2 v = *(const float2*)&A[(long)(r0 + r) * ld_in + c0 + 2 * tx];
    tile[r][2 * tx] = v.x;
    tile[r][2 * tx + 1] = v.y;
  }
  __syncthreads();
#pragma unroll
  for (int i = 0; i < 8; i++) {
    int c = ty + 8 * i;
    ushort2 o;
    o.x = f2bf(tile[2 * tx][c]);
    o.y = f2bf(tile[2 * tx + 1][c]);
    *(ushort2*)&O[(long)(c0 + c) * ld_out + r0 + 2 * tx] = o;
  }
}

__global__ void k_norm_to_bc(const float* __restrict__ norm, u16* __restrict__ bc) {
  int h = blockIdx.y;
  int i = blockIdx.x * 256 + threadIdx.x;  // 0..16383
  bc[(long)h * 32768 + 16384 + i] = f2bf(norm[(long)h * 16384 + i]);
}

// ---------------- GEMM v4: C[M,N] = A[M,K]bf16 @ Bt[N,K]bf16^T ----------------
// BM=256 BN=128 BK=32, 256 thr (4 waves 2x2, per-wave 128x64), triple-buffered
// LDS (3 x 24 KiB = 72 KiB -> 2 blocks/CU). Stages issued 2 tiles ahead,
// counted vmcnt(6) + one raw s_barrier per K-tile. Swizzle: 16B-colblock
// blk = cb ^ ((row>>1)&3) on both pre-swizzled global source and ds_read.

__global__ __launch_bounds__(256, 2) void k_gemm4(
    const u16* __restrict__ A, const u16* __restrict__ Bt, void* __restrict__ Cv,
    int K, int ldc, long strideA, long strideB, long strideC, int bmodB, int obf) {
  __shared__ __align__(16) u16 lds[3 * 12288];  // per buf: A[256][32]=8192 u16, B[128][32]=4096 u16
  const int bz = blockIdx.z;
  const u16* Ap = A + (long)bz * strideA;
  const u16* Bp = Bt + (long)(bz % bmodB) * strideB;
  const long coff = (long)bz * strideC;

  // XCD-bijective block swizzle over x*y (all call sites have nwg % 8 == 0)
  const int gx = gridDim.x;
  const int nwg = gx * gridDim.y;
  int id = blockIdx.y * gx + blockIdx.x;
  if (!(nwg & 7)) { int q = nwg >> 3; id = (id & 7) * q + (id >> 3); }
  const int n0 = (id % gx) * 128, m0 = (id / gx) * 256;

  const int tid = threadIdx.x, wid = tid >> 6, lane = tid & 63;
  const int l15 = lane & 15, lhi = lane >> 4;
  const int wm = wid >> 1, wn = wid & 1;  // per-wave 128 rows x 64 cols

  // stage source bases (pre-swizzled global, u16 element offsets)
  const int swc = ((lane & 3) ^ ((lane >> 3) & 3)) * 8;
  const long gA0 = (long)(m0 + (lane >> 2)) * K + swc;
  const long gB0 = (long)(n0 + (lane >> 2)) * K + swc;

  // ds_read fragment bases (swizzled); +q*512 per 16-row step
  const int swr = ((lhi ^ ((l15 >> 1) & 3)) * 8);
  const int abase = (wm * 128 + l15) * 32 + swr;
  const int bbase = 8192 + (wn * 64 + l15) * 32 + swr;

  const int KT = K >> 5;
  f32x4 acc[8][4];
#pragma unroll
  for (int i = 0; i < 8; i++)
#pragma unroll
    for (int j = 0; j < 4; j++) acc[i][j] = (f32x4){0.f, 0.f, 0.f, 0.f};

  // prologue: stage tiles 0 and 1 (6 wave-loads each)
#pragma unroll
  for (int tt = 0; tt < 2; tt++) {
    u16* sb = &lds[tt * 12288];
    const long ko = (long)tt * 32;
#pragma unroll
    for (int it = 0; it < 4; it++)
      gl_lds16(Ap + gA0 + (long)((it * 4 + wid) * 16) * K + ko, &sb[(it * 4 + wid) * 512]);
#pragma unroll
    for (int it = 0; it < 2; it++)
      gl_lds16(Bp + gB0 + (long)((it * 4 + wid) * 16) * K + ko, &sb[8192 + (it * 4 + wid) * 512]);
  }
  asm volatile("s_waitcnt vmcnt(6)" ::: "memory");
  __builtin_amdgcn_s_barrier();
  asm volatile("" ::: "memory");

  int b = 0;
  for (int t = 0; t < KT; ++t) {
    const int sbi = (b + 2 >= 3) ? (b - 1) : (b + 2);
    const u16* lb = &lds[b * 12288];
    u16* sb = &lds[sbi * 12288];
    const bool dst = (t + 2) < KT;
    const long ko = (long)(t + 2) * 32;

    bf16x8 bfr[4];
#pragma unroll
    for (int nq = 0; nq < 4; nq++) bfr[nq] = *(const bf16x8*)&lb[bbase + nq * 512];

#pragma unroll
    for (int ph = 0; ph < 4; ph++) {
      bf16x8 a0 = *(const bf16x8*)&lb[abase + (2 * ph) * 512];
      bf16x8 a1 = *(const bf16x8*)&lb[abase + (2 * ph + 1) * 512];
      if (dst) {
        if (ph == 0) {
          gl_lds16(Ap + gA0 + (long)((0 * 4 + wid) * 16) * K + ko, &sb[(0 * 4 + wid) * 512]);
          gl_lds16(Ap + gA0 + (long)((1 * 4 + wid) * 16) * K + ko, &sb[(1 * 4 + wid) * 512]);
        } else if (ph == 1) {
          gl_lds16(Ap + gA0 + (long)((2 * 4 + wid) * 16) * K + ko, &sb[(2 * 4 + wid) * 512]);
          gl_lds16(Ap + gA0 + (long)((3 * 4 + wid) * 16) * K + ko, &sb[(3 * 4 + wid) * 512]);
        } else if (ph == 2) {
          gl_lds16(Bp + gB0 + (long)((0 * 4 + wid) * 16) * K + ko, &sb[8192 + (0 * 4 + wid) * 512]);
          gl_lds16(Bp + gB0 + (long)((1 * 4 + wid) * 16) * K + ko, &sb[8192 + (1 * 4 + wid) * 512]);
        }
      }
      __builtin_amdgcn_s_setprio(1);
#pragma unroll
      for (int nq = 0; nq < 4; nq++) {
        acc[2 * ph][nq] = __builtin_amdgcn_mfma_f32_16x16x32_bf16(a0, bfr[nq], acc[2 * ph][nq], 0, 0, 0);
        acc[2 * ph + 1][nq] = __builtin_amdgcn_mfma_f32_16x16x32_bf16(a1, bfr[nq], acc[2 * ph + 1][nq], 0, 0, 0);
      }
      __builtin_amdgcn_s_setprio(0);
    }

    if (t + 1 < KT) {
      if (dst)
        asm volatile("s_waitcnt vmcnt(6)" ::: "memory");
      else
        asm volatile("s_waitcnt vmcnt(0)" ::: "memory");
      __builtin_amdgcn_s_barrier();
      asm volatile("" ::: "memory");
    }
    b = (b + 1 >= 3) ? 0 : (b + 1);
  }

#pragma unroll
  for (int mi = 0; mi < 8; mi++)
#pragma unroll
    for (int ni = 0; ni < 4; ni++)
#pragma unroll
      for (int j = 0; j < 4; j++) {
        long row = m0 + wm * 128 + mi * 16 + lhi * 4 + j;
        long col = n0 + wn * 64 + ni * 16 + l15;
        if (obf)
          ((u16*)Cv)[coff + row * ldc + col] = f2bf(acc[mi][ni][j]);
        else
          ((float*)Cv)[coff + row * ldc + col] = acc[mi][ni][j];
      }
}

// ---------------- fused qn + rope ----------------

__global__ void k_rope_table(const int* __restrict__ pos, float* __restrict__ ct,
                             float* __restrict__ st) {
  int s = blockIdx.x, i = threadIdx.x;  // 64 threads
  float p = (float)pos[s];
  float ang = p * expf(-(float)i * (9.210340371976184f / 64.0f));
  ct[s * 64 + i] = cosf(ang);
  st[s * 64 + i] = sinf(ang);
}

__global__ void k_qnrope(const float* __restrict__ qkv, const float* __restrict__ ct,
                         const float* __restrict__ st, u16* __restrict__ qnb,
                         u16* __restrict__ qrb, u16* __restrict__ knb,
                         u16* __restrict__ krb, float* __restrict__ knf) {
  int s = blockIdx.x, y = blockIdx.y, l = threadIdx.x;  // 64 threads
  bool isq = y < NH;
  int h = isq ? y : y - NH;
  const float* row = qkv + (long)s * QKV_N + (isq ? h * HD : HID_DIM + h * HD);
  float x0 = row[l], x1 = row[l + 64];
  float f0 = x0 > 0.f ? x0 + 1.f : __expf(x0);
  float f1 = x1 > 0.f ? x1 + 1.f : __expf(x1);
  float sum = f0 + f1;
#pragma unroll
  for (int m = 32; m >= 1; m >>= 1) sum += __shfl_xor(sum, m);
  float inv = 1.f / (sum + 1e-8f);
  float y0 = f0 * inv, y1 = f1 * inv;
  long o = ((long)h * S_LEN + s) * HD;
  float c = ct[s * 64 + l], sn = st[s * 64 + l];
  u16 r0 = f2bf(x0 * c - x1 * sn), r1 = f2bf(x1 * c + x0 * sn);
  if (isq) {
    qnb[o + l] = f2bf(y0); qnb[o + l + 64] = f2bf(y1);
    qrb[o + l] = r0; qrb[o + l + 64] = r1;
  } else {
    knb[o + l] = f2bf(y0); knb[o + l + 64] = f2bf(y1);
    knf[o + l] = y0; knf[o + l + 64] = y1;
    krb[o + l] = r0; krb[o + l + 64] = r1;
  }
}

// ---------------- U = v - v_ret ----------------

__global__ void k_uvret(const u16* __restrict__ rawk, const float* __restrict__ qkv,
                        float* __restrict__ U) {
  int s = blockIdx.x, h = blockIdx.y, e = threadIdx.x;  // 128 threads
  long base = ((long)h * S_LEN + s) * 256;
  float num = bf2f(rawk[base + e]), den = bf2f(rawk[base + 128 + e]);
  U[((long)h * S_LEN + s) * HD + e] =
      qkv[(long)s * QKV_N + HID_DIM + NKV * HD + h * HD + e] - num / (den + 1e-8f);
}

// ---------------- flash attention v2 ----------------

__global__ __launch_bounds__(256) void k_flash2(
    const u16* __restrict__ qr, const u16* __restrict__ kr,
    const u16* __restrict__ vt, float* __restrict__ attn) {
  __shared__ u16 Ks[64 * 128];      // [kv 64][d 128] swizzled
  __shared__ u16 Vs[128 * 64];      // [d 128][kv 64] swizzled
  __shared__ u16 Ps[4][16 * 64];    // per-wave [q 16][kv 64] swizzled
  const int bx = blockIdx.x, h = blockIdx.y;
  const int hk = h >> 2;  // GROUPS=4, repeat_interleave
  const int tid = threadIdx.x, wid = tid >> 6, lane = tid & 63;
  const int l15 = lane & 15, lhi = lane >> 4;
  const u16* qbase = qr + (long)h * S_LEN * HD;
  const u16* kb0 = kr + (long)hk * S_LEN * HD;
  const u16* vb0 = vt + (long)hk * HD * S_LEN;
  float* ob = attn + (long)h * S_LEN * HD;
  u16* P = Ps[wid];

  for (int si = 0; si < 2; si++) {
    const int s = si ? (31 - bx) : bx;
    const int qs = s * 64 + wid * 16;
    bf16x8 aq[4];
#pragma unroll
    for (int kc = 0; kc < 4; kc++)
      aq[kc] = *(const bf16x8*)&qbase[(long)(qs + l15) * HD + kc * 32 + lhi * 8];
    f32x4 accO[8];
#pragma unroll
    for (int i = 0; i < 8; i++) accO[i] = (f32x4){0.f, 0.f, 0.f, 0.f};
    float rs[4] = {0.f, 0.f, 0.f, 0.f};

    for (int t = 0; t <= s; t++) {
      __syncthreads();
#pragma unroll
      for (int it = 0; it < 4; it++) {
        int chunk = it * 4 + wid;
        int r = chunk * 4 + (lane >> 4);
        int sc = ((lane & 15) * 8) ^ ((r & 7) * 8);
        gl_lds16(kb0 + (long)(t * 64 + r) * HD + sc, &Ks[chunk * 512]);
      }
#pragma unroll
      for (int it = 0; it < 4; it++) {
        int chunk = it * 4 + wid;
        int r = chunk * 8 + (lane >> 3);
        int sc = ((lane & 7) * 8) ^ ((r & 7) * 8);
        gl_lds16(vb0 + (long)r * S_LEN + t * 64 + sc, &Vs[chunk * 512]);
      }
      asm volatile("s_waitcnt vmcnt(0)" ::: "memory");
      __syncthreads();

      f32x4 accS[4];
#pragma unroll
      for (int i = 0; i < 4; i++) accS[i] = (f32x4){0.f, 0.f, 0.f, 0.f};
#pragma unroll
      for (int ni = 0; ni < 4; ni++) {
        int row = ni * 16 + l15;
#pragma unroll
        for (int kc = 0; kc < 4; kc++) {
          bf16x8 bk = *(const bf16x8*)&Ks[row * 128 + ((kc * 32 + lhi * 8) ^ ((row & 7) * 8))];
          accS[ni] = __builtin_amdgcn_mfma_f32_16x16x32_bf16(aq[kc], bk, accS[ni], 0, 0, 0);
        }
      }
      const bool diag = (t == s);
#pragma unroll
      for (int ni = 0; ni < 4; ni++) {
        int col = t * 64 + ni * 16 + l15;
#pragma unroll
        for (int j = 0; j < 4; j++) {
          int row = qs + lhi * 4 + j;
          float p = (!diag || col <= row) ? __expf(accS[ni][j] * SCALE_F) : 0.f;
          rs[j] += p;
          int pr = lhi * 4 + j;
          P[pr * 64 + ((ni * 16 + l15) ^ ((pr & 7) * 8))] = f2bf(p);
        }
      }
      asm volatile("s_waitcnt lgkmcnt(0)" ::: "memory");
      __builtin_amdgcn_sched_barrier(0);
      bf16x8 ap[2];
#pragma unroll
      for (int ks = 0; ks < 2; ks++)
        ap[ks] = *(const bf16x8*)&P[l15 * 64 + ((ks * 32 + lhi * 8) ^ ((l15 & 7) * 8))];
#pragma unroll
      for (int nj = 0; nj < 8; nj++) {
        int row = nj * 16 + l15;
#pragma unroll
        for (int ks = 0; ks < 2; ks++) {
          bf16x8 bv = *(const bf16x8*)&Vs[row * 64 + ((ks * 32 + lhi * 8) ^ ((row & 7) * 8))];
          accO[nj] = __builtin_amdgcn_mfma_f32_16x16x32_bf16(ap[ks], bv, accO[nj], 0, 0, 0);
        }
      }
    }
#pragma unroll
    for (int j = 0; j < 4; j++) {
      float v = rs[j];
      v += __shfl_xor(v, 1);
      v += __shfl_xor(v, 2);
      v += __shfl_xor(v, 4);
      v += __shfl_xor(v, 8);
      rs[j] = 1.f / v;
    }
#pragma unroll
    for (int nj = 0; nj < 8; nj++)
#pragma unroll
      for (int j = 0; j < 4; j++)
        ob[(long)(qs + lhi * 4 + j) * HD + nj * 16 + l15] = accO[nj][j] * rs[j];
  }
}

// ---------------- combine ----------------

__global__ void k_combine(const u16* __restrict__ rawq, const float* __restrict__ attn,
                          const float* __restrict__ beta, u16* __restrict__ comb) {
  int s = blockIdx.x, h = blockIdx.y, d = threadIdx.x;  // 128 threads
  float g = 1.f / (1.f + __expf(-beta[0]));
  long b = ((long)h * S_LEN + s) * 256;
  float mo = bf2f(rawq[b + d]) / (bf2f(rawq[b + 128 + d]) + 1e-8f);
  float ao = attn[((long)h * S_LEN + s) * HD + d];
  comb[(long)s * HID_DIM + h * HD + d] = f2bf(g * mo + (1.f - g) * ao);
}

// ---------------- delta-rule memory / norm updates (f32 exact path) ----------------

__global__ void k_delta_part(const float* __restrict__ knf, const float* __restrict__ U,
                             float* __restrict__ dpart) {
  int d0 = blockIdx.x * 16, h = blockIdx.y, c = blockIdx.z, e = threadIdx.x;
  const float* kh = knf + (long)h * S_LEN * HD + (long)c * 512 * HD;
  const float* Uh = U + (long)h * S_LEN * HD + (long)c * 512 * HD;
  float a[16];
#pragma unroll
  for (int d = 0; d < 16; d++) a[d] = 0.f;
  for (int s = 0; s < 512; s++) {
    float u = Uh[(long)s * HD + e];
    const float* kr = &kh[(long)s * HD + d0];
#pragma unroll
    for (int d = 0; d < 16; d++) a[d] += kr[d] * u;
  }
  long ob = (long)c * (NKV * HD * HD) + (long)h * HD * HD + (long)d0 * HD + e;
#pragma unroll
  for (int d = 0; d < 16; d++) dpart[ob + (long)d * HD] = a[d];
}

__global__ void k_delta_reduce(const float* __restrict__ dpart, const float* __restrict__ mem,
                               float* __restrict__ outmem) {
  long i = (long)blockIdx.x * 256 + threadIdx.x;  // 131072
  const long N = (long)NKV * HD * HD;
  float a = dpart[i] + dpart[N + i] + dpart[2 * N + i] + dpart[3 * N + i];
  outmem[i] = mem[i] + a;
}

__global__ void k_norm_part(const float* __restrict__ knf, float* __restrict__ npart) {
  int c = blockIdx.x, h = blockIdx.y, j = threadIdx.x;  // 16 x 8, 128 thr
  const float* kh = knf + (long)h * S_LEN * HD + (long)c * 128 * HD;
  float a = 0.f;
  for (int s = 0; s < 128; s++) a += kh[(long)s * HD + j];
  npart[((long)c * NKV + h) * HD + j] = a;
}

__global__ void k_norm_write(const float* __restrict__ npart, const float* __restrict__ norm,
                             float* __restrict__ outn) {
  int h = blockIdx.x, j = threadIdx.x;  // 8 blocks, 128 thr
  float cs = 0.f;
  for (int c = 0; c < 16; c++) cs += npart[((long)c * NKV + h) * HD + j];
  long ob = (long)h * HD * HD;
  for (int i = 0; i < HD; i++) outn[ob + (long)i * HD + j] = norm[ob + (long)i * HD + j] + cs;
}

// ---------------- host ----------------
// Aliased arena (stream-serialized), same map as round 2/3 (peak 154.5 MiB).

extern "C" void kernel_launch(void* const* d_in, const int* in_sizes, int n_in,
                              void* d_out, int out_size, void* d_ws, size_t ws_size,
                              hipStream_t stream) {
  const float* hs = (const float*)d_in[0];
  const int* pos = (const int*)d_in[1];
  const float* wq = (const float*)d_in[2];
  const float* wk = (const float*)d_in[3];
  const float* wv = (const float*)d_in[4];
  const float* wo = (const float*)d_in[5];
  const float* memf = (const float*)d_in[6];
  const float* normf = (const float*)d_in[7];
  const float* beta = (const float*)d_in[8];
  (void)in_sizes; (void)n_in; (void)out_size; (void)ws_size;

  float* out = (float*)d_out;
  float* out_mem = out + (long)S_LEN * HID_DIM;
  float* out_norm = out_mem + NKV * HD * HD;

  const size_t MB = 1u << 20;
  char* w = (char*)d_ws;
  u16* hsb    = (u16*)(w + 0);
  u16* qnb    = (u16*)(w + 0);
  u16* comb   = (u16*)(w + 0);
  float* dpart= (float*)(w + 0);
  float* npart= (float*)(w + 2 * MB);
  u16* wT6    = (u16*)(w + 16 * MB);
  u16* rawq   = (u16*)(w + 16 * MB);
  u16* woT    = (u16*)(w + 16 * MB);
  u16* rawk   = (u16*)(w + 48 * MB);
  float* ctab = (float*)(w + 56 * MB);
  float* stab = (float*)(w + 56 * MB + 512 * 1024);
  u16* bc     = (u16*)(w + 57 * MB);
  u16* vtb    = (u16*)(w + 57 * MB + 512 * 1024);
  float* qkvf = (float*)(w + 66 * MB + 512 * 1024);
  float* attn = (float*)(w + 66 * MB + 512 * 1024);
  float* Ub   = (float*)(w + 114 * MB + 512 * 1024);
  float* knf  = (float*)(w + 122 * MB + 512 * 1024);
  u16* qrb    = (u16*)(w + 130 * MB + 512 * 1024);
  u16* krb    = (u16*)(w + 146 * MB + 512 * 1024);
  u16* knb    = (u16*)(w + 150 * MB + 512 * 1024);

  // --- A: conversions + fused QKV projection ---
  k_f32_to_bf16<<<dim3((S_LEN * HID_DIM / 4 + 255) / 256), dim3(256), 0, stream>>>(
      hs, hsb, (long)(S_LEN * HID_DIM / 4));
  k_tr64<<<dim3(64, 64, 1), dim3(256), 0, stream>>>(
      wq, wT6, HID_DIM, HID_DIM, 0L, 0L);
  k_tr64<<<dim3(16, 64, 1), dim3(256), 0, stream>>>(
      wk, wT6 + (long)HID_DIM * HID_DIM, 1024, HID_DIM, 0L, 0L);
  k_tr64<<<dim3(16, 64, 1), dim3(256), 0, stream>>>(
      wv, wT6 + (long)(HID_DIM + 1024) * HID_DIM, 1024, HID_DIM, 0L, 0L);
  k_gemm4<<<dim3(QKV_N / 128, S_LEN / 256, 1), dim3(256), 0, stream>>>(
      hsb, wT6, qkvf, HID_DIM, QKV_N, 0L, 0L, 0L, 1, 0);

  // --- D: qn + rope fused ---
  k_rope_table<<<dim3(S_LEN), dim3(64), 0, stream>>>(pos, ctab, stab);
  k_qnrope<<<dim3(S_LEN, NH + NKV), dim3(64), 0, stream>>>(
      qkvf, ctab, stab, qnb, qrb, knb, krb, knf);

  // --- E: V^T per kv head; bc = [mem^T | norm] bf16 ---
  k_tr64<<<dim3(2, 32, NKV), dim3(256), 0, stream>>>(
      qkvf + HID_DIM + NKV * HD, vtb, QKV_N, S_LEN, 128L, (long)(HD * S_LEN));
  k_tr64<<<dim3(2, 2, NKV), dim3(256), 0, stream>>>(
      memf, bc, HD, HD, (long)(HD * HD), (long)(256 * HD));
  k_norm_to_bc<<<dim3(64, NKV), dim3(256), 0, stream>>>(normf, bc);

  // --- F: retrieval raws (batched, bf16 out) ---
  k_gemm4<<<dim3(2, 8, NH), dim3(256), 0, stream>>>(
      qnb, bc, rawq, HD, 256, (long)(S_LEN * HD), (long)(256 * HD),
      (long)(S_LEN * 256), NKV, 1);
  k_gemm4<<<dim3(2, 8, NKV), dim3(256), 0, stream>>>(
      knb, bc, rawk, HD, 256, (long)(S_LEN * HD), (long)(256 * HD),
      (long)(S_LEN * 256), NKV, 1);

  // --- G: U = v - v_ret ---
  k_uvret<<<dim3(S_LEN, NKV), dim3(128), 0, stream>>>(rawk, qkvf, Ub);

  // --- H: attention ---
  k_flash2<<<dim3(16, NH), dim3(256), 0, stream>>>(qrb, krb, vtb, attn);

  // --- I: combine ---
  k_combine<<<dim3(S_LEN, NH), dim3(128), 0, stream>>>(rawq, attn, beta, comb);

  // --- J: wo^T; output projection ---
  k_tr64<<<dim3(64, 64, 1), dim3(256), 0, stream>>>(
      wo, woT, HID_DIM, HID_DIM, 0L, 0L);
  k_gemm4<<<dim3(HID_DIM / 128, S_LEN / 256, 1), dim3(256), 0, stream>>>(
      comb, woT, out, HID_DIM, HID_DIM, 0L, 0L, 0L, 1, 0);

  // --- K: memory / norm updates ---
  k_delta_part<<<dim3(8, NKV, 4), dim3(128), 0, stream>>>(knf, Ub, dpart);
  k_delta_reduce<<<dim3(512), dim3(256), 0, stream>>>(dpart, memf, out_mem);
  k_norm_part<<<dim3(16, NKV), dim3(128), 0, stream>>>(knf, npart);
  k_norm_write<<<dim3(NKV), dim3(128), 0, stream>>>(npart, normf, out_norm);
}